// Round 7
// baseline (392.735 us; speedup 1.0000x reference)
//
#include <hip/hip_runtime.h>
#include <float.h>

#define BATCH 8
#define SEQ   1024
#define CDIM  512
#define HEADS 8
#define HD    64
#define TOPK  16
#define MTOT  (BATCH*SEQ)   // 8192

typedef short bf16x8 __attribute__((ext_vector_type(8)));
typedef float f32x4v __attribute__((ext_vector_type(4)));

// round-to-nearest bf16 split: f = hi + lo, each bf16; |err| ~ 2^-17 |f|
__device__ inline void bf16split(float f, unsigned short& h, unsigned short& l) {
    unsigned u = __float_as_uint(f);
    unsigned hr = (u + 0x7fffu + ((u >> 16) & 1u)) >> 16;
    h = (unsigned short)hr;
    float rest = f - __uint_as_float(hr << 16);
    unsigned v = __float_as_uint(rest);
    l = (unsigned short)((v + 0x7fffu + ((v >> 16) & 1u)) >> 16);
}

// ============================================================
// Prep 1: split x into bf16 hi/lo planes (row-major [8192][512])
// ============================================================
__global__ __launch_bounds__(256) void split_x_kernel(
    const float* __restrict__ x,
    unsigned short* __restrict__ xhi, unsigned short* __restrict__ xlo)
{
    size_t i = ((size_t)blockIdx.x * 256 + threadIdx.x) * 4;
    float4 v = *(const float4*)(x + i);
    ushort4 h, l;
    bf16split(v.x, h.x, l.x); bf16split(v.y, h.y, l.y);
    bf16split(v.z, h.z, l.z); bf16split(v.w, h.w, l.w);
    *(ushort4*)(xhi + i) = h;
    *(ushort4*)(xlo + i) = l;
}

// ============================================================
// Prep 2: transpose + split weights.
//   BT  [1536][512] = concat(Wq, Wkv) columns as rows (bf16 hi/lo)
//   WpT [512][512]  = Wp columns as rows (bf16 hi/lo)
// ============================================================
__global__ __launch_bounds__(256) void split_wT_kernel(
    const float* __restrict__ Wq, const float* __restrict__ Wkv,
    const float* __restrict__ Wp,
    unsigned short* __restrict__ bThi, unsigned short* __restrict__ bTlo,
    unsigned short* __restrict__ wpThi, unsigned short* __restrict__ wpTlo)
{
    __shared__ float tile[64][65];
    const int ct = blockIdx.x, k0 = blockIdx.y * 64, t = threadIdx.x;
    const float* src; int ld, sc0, dr0;
    unsigned short *dhi, *dlo;
    if (ct < 8)       { src = Wq;  ld = CDIM;     sc0 = ct * 64;        dr0 = ct * 64;              dhi = bThi;  dlo = bTlo;  }
    else if (ct < 24) { src = Wkv; ld = 2 * CDIM; sc0 = (ct - 8) * 64;  dr0 = CDIM + (ct - 8) * 64; dhi = bThi;  dlo = bTlo;  }
    else              { src = Wp;  ld = CDIM;     sc0 = (ct - 24) * 64; dr0 = (ct - 24) * 64;       dhi = wpThi; dlo = wpTlo; }

    #pragma unroll
    for (int i = 0; i < 4; i++) {
        int f = t + i * 256;          // 0..1023
        int r = f >> 4, c4 = f & 15;  // k-row, col-segment
        float4 v = *(const float4*)(src + (size_t)(k0 + r) * ld + sc0 + c4 * 4);
        tile[c4*4+0][r] = v.x; tile[c4*4+1][r] = v.y;
        tile[c4*4+2][r] = v.z; tile[c4*4+3][r] = v.w;
    }
    __syncthreads();
    #pragma unroll
    for (int i = 0; i < 2; i++) {
        int f = t + i * 256;          // 0..511
        int c = f >> 3, ko = f & 7;
        const float* tp = &tile[c][ko * 8];
        ushort4 h0, l0, h1, l1;
        bf16split(tp[0], h0.x, l0.x); bf16split(tp[1], h0.y, l0.y);
        bf16split(tp[2], h0.z, l0.z); bf16split(tp[3], h0.w, l0.w);
        bf16split(tp[4], h1.x, l1.x); bf16split(tp[5], h1.y, l1.y);
        bf16split(tp[6], h1.z, l1.z); bf16split(tp[7], h1.w, l1.w);
        size_t o = (size_t)(dr0 + c) * CDIM + k0 + ko * 8;
        *(ushort4*)(dhi + o)     = h0; *(ushort4*)(dhi + o + 4) = h1;
        *(ushort4*)(dlo + o)     = l0; *(ushort4*)(dlo + o + 4) = l1;
    }
}

// ============================================================
// Shared MFMA GEMM core: C[128x128] = A[128xK] * B^T[128xK]^T, K=512,
// split-bf16 3-product (hi*hi + hi*lo + lo*hi), fp32 accumulate.
// NEW (round 7): barrier-free, LDS-free register pipeline.
// Round-6 profile: MfmaUtil 22 / VALU 16 / HBM 15 / occ 17 — nothing
// saturated; latency-bound on the per-K-step vmcnt(0)+barrier. Because
// A and B are pre-transposed [row][k], each lane's MFMA fragment is
// DIRECTLY loadable from global with perfect coalescing (4 lanes/row
// cover one 64B line) — the LDS was a pure bounce buffer. Now each
// wave double-buffers fragments in registers: load step t+1 while
// MFMA-ing step t. No __syncthreads, no LDS, waves fully decoupled.
// Costs 2x L2 traffic (no intra-block tile sharing) ~= 22 us of L2 BW.
// ============================================================
__device__ __forceinline__ void ld_frag4(uint4* d, const unsigned short* p) {
    d[0] = *(const uint4*)(p);
    d[1] = *(const uint4*)(p + 16 * CDIM);
    d[2] = *(const uint4*)(p + 32 * CDIM);
    d[3] = *(const uint4*)(p + 48 * CDIM);
}

__device__ __forceinline__ void mfma_step(
    const uint4* ah, const uint4* al, const uint4* bh, const uint4* bl,
    f32x4v acc[4][4])
{
    #pragma unroll
    for (int i = 0; i < 4; i++) {
        bf16x8 afh = *(const bf16x8*)&ah[i];
        bf16x8 afl = *(const bf16x8*)&al[i];
        #pragma unroll
        for (int j = 0; j < 4; j++) {
            bf16x8 bfh = *(const bf16x8*)&bh[j];
            bf16x8 bfl = *(const bf16x8*)&bl[j];
            acc[i][j] = __builtin_amdgcn_mfma_f32_16x16x32_bf16(bfh, afh, acc[i][j], 0, 0, 0);
            acc[i][j] = __builtin_amdgcn_mfma_f32_16x16x32_bf16(bfh, afl, acc[i][j], 0, 0, 0);
            acc[i][j] = __builtin_amdgcn_mfma_f32_16x16x32_bf16(bfl, afh, acc[i][j], 0, 0, 0);
        }
    }
}

__device__ __forceinline__ void mfma_gemm_core(
    const unsigned short* __restrict__ ahi, const unsigned short* __restrict__ alo,
    const unsigned short* __restrict__ bhi, const unsigned short* __restrict__ blo,
    int row0, int col0, int lane, int w, f32x4v acc[4][4])
{
    const int wr = w >> 1, wc = w & 1;
    const int lrow = lane & 15, koct = (lane >> 4) * 8;
    // fragment c (of this wave's 4): rows +c*16; lane holds row lrow, k-octet koct
    const unsigned short* pah = ahi + (size_t)(row0 + wr * 64 + lrow) * CDIM + koct;
    const unsigned short* pal = alo + (size_t)(row0 + wr * 64 + lrow) * CDIM + koct;
    const unsigned short* pbh = bhi + (size_t)(col0 + wc * 64 + lrow) * CDIM + koct;
    const unsigned short* pbl = blo + (size_t)(col0 + wc * 64 + lrow) * CDIM + koct;

    #pragma unroll
    for (int i = 0; i < 4; i++)
        #pragma unroll
        for (int j = 0; j < 4; j++)
            acc[i][j] = (f32x4v){0.f, 0.f, 0.f, 0.f};

    uint4 cah[4], cal_[4], cbh[4], cbl_[4];   // current K-step fragments
    uint4 nah[4], nal_[4], nbh[4], nbl_[4];   // next K-step fragments

    ld_frag4(cah, pah);  ld_frag4(cal_, pal);
    ld_frag4(cbh, pbh);  ld_frag4(cbl_, pbl);

    for (int kt = 0; kt < CDIM; kt += 64) {
        // prefetch kt+32 (always valid: last kt=448 -> 480 < 512)
        ld_frag4(nah, pah + kt + 32);  ld_frag4(nal_, pal + kt + 32);
        ld_frag4(nbh, pbh + kt + 32);  ld_frag4(nbl_, pbl + kt + 32);
        mfma_step(cah, cal_, cbh, cbl_, acc);
        if (kt + 64 < CDIM) {
            ld_frag4(cah, pah + kt + 64);  ld_frag4(cal_, pal + kt + 64);
            ld_frag4(cbh, pbh + kt + 64);  ld_frag4(cbl_, pbl + kt + 64);
        }
        mfma_step(nah, nal_, nbh, nbl_, acc);
    }
}

// ============================================================
// Kernel 1: QKV projection via MFMA.
// ============================================================
__global__ __launch_bounds__(256, 2) void qkv_mfma_kernel(
    const unsigned short* __restrict__ xhi, const unsigned short* __restrict__ xlo,
    const unsigned short* __restrict__ bThi, const unsigned short* __restrict__ bTlo,
    const float* __restrict__ bq, const float* __restrict__ bkv,
    unsigned short* __restrict__ qhi_g, unsigned short* __restrict__ qlo_g,
    unsigned short* __restrict__ khi_g, unsigned short* __restrict__ klo_g,
    float* __restrict__ v_ws)
{
    const int tid = threadIdx.x, lane = tid & 63, w = tid >> 6;
    const int row0 = blockIdx.x * 128, col0 = blockIdx.y * 128;

    f32x4v acc[4][4];
    mfma_gemm_core(xhi, xlo, bThi, bTlo, row0, col0, lane, w, acc);

    const int wr = w >> 1, wc = w & 1;
    const bool isq = (col0 < CDIM);
    #pragma unroll
    for (int i = 0; i < 4; i++) {
        int rG = row0 + (wr*4 + i) * 16 + (lane & 15);
        int bb = rG >> 10, nn = rG & (SEQ - 1);
        #pragma unroll
        for (int j = 0; j < 4; j++) {
            int cG = col0 + (wc*4 + j) * 16 + (lane >> 4) * 4;
            float4 bias4 = isq ? *(const float4*)(bq + cG)
                               : *(const float4*)(bkv + cG - CDIM);
            float4 val;
            val.x = acc[i][j][0] + bias4.x;
            val.y = acc[i][j][1] + bias4.y;
            val.z = acc[i][j][2] + bias4.z;
            val.w = acc[i][j][3] + bias4.w;
            if (isq) {
                val.x = fmaxf(val.x, 0.f); val.y = fmaxf(val.y, 0.f);
                val.z = fmaxf(val.z, 0.f); val.w = fmaxf(val.w, 0.f);
                int hq = cG >> 6, d = cG & 63;
                size_t base = (((size_t)bb * HEADS + hq) * SEQ + nn) * HD + d;
                ushort4 hv, lv;
                bf16split(val.x, hv.x, lv.x); bf16split(val.y, hv.y, lv.y);
                bf16split(val.z, hv.z, lv.z); bf16split(val.w, hv.w, lv.w);
                *(ushort4*)(qhi_g + base) = hv;
                *(ushort4*)(qlo_g + base) = lv;
            } else {
                int c2 = cG - CDIM;
                int t = c2 >> 9, hq = (c2 >> 6) & 7, d = c2 & 63;
                size_t base = (((size_t)bb * HEADS + hq) * SEQ + nn) * HD + d;
                if (t == 0) {
                    ushort4 hv, lv;
                    bf16split(val.x, hv.x, lv.x); bf16split(val.y, hv.y, lv.y);
                    bf16split(val.z, hv.z, lv.z); bf16split(val.w, hv.w, lv.w);
                    *(ushort4*)(khi_g + base) = hv;
                    *(ushort4*)(klo_g + base) = lv;
                } else {
                    *(float4*)(v_ws + base) = val;
                }
            }
        }
    }
}

// ============================================================
// Kernel 2: per-(b,h) column sum of V  -> vsum[bh][64]
// ============================================================
__global__ __launch_bounds__(256) void vsum_kernel(
    const float* __restrict__ v_ws, float* __restrict__ vsum_ws)
{
    __shared__ float red[4][HD];
    const int bh = blockIdx.x;
    const int d  = threadIdx.x & 63;
    const int sl = threadIdx.x >> 6;
    const float* vh = v_ws + (size_t)bh * SEQ * HD;
    float s = 0.f;
    for (int m = sl * 256; m < (sl + 1) * 256; m++) s += vh[(size_t)m * HD + d];
    red[sl][d] = s;
    __syncthreads();
    if (threadIdx.x < HD)
        vsum_ws[(size_t)bh * HD + d] = red[0][d] + red[1][d] + red[2][d] + red[3][d];
}

// ============================================================
// Kernel A: MFMA split-bf16 scores -> global fp32 [bhl][1024][1024]
// (scaled by D^-0.5). Double-buffered K tiles.
// ============================================================
__global__ __launch_bounds__(256) void score_kernel(
    const unsigned short* __restrict__ qhi_g, const unsigned short* __restrict__ qlo_g,
    const unsigned short* __restrict__ khi_g, const unsigned short* __restrict__ klo_g,
    float* __restrict__ s_g, int bh0)
{
    __shared__ __align__(16) short qhi_s[4096], qlo_s[4096];
    __shared__ __align__(16) short khi_s[2][4096], klo_s[2][4096];

    const int bhl = blockIdx.y;
    const int bh  = bh0 + bhl;
    const int n0  = blockIdx.x * 64;
    const int tid = threadIdx.x;
    const int lane = tid & 63, w = tid >> 6;
    const int r_st = tid >> 2, c4 = tid & 3;
    const size_t hb = (size_t)bh * SEQ * HD;

    const int s0 = c4 * 2, s1 = s0 + 1;
    const int cx0 = ((r_st >> 4)*2 + (s0 >> 2))*64 + (s0 & 3)*16 + (r_st & 15);
    const int cx1 = ((r_st >> 4)*2 + (s1 >> 2))*64 + (s1 & 3)*16 + (r_st & 15);

    {
        const unsigned short* qp  = qhi_g + hb + (size_t)(n0 + r_st)*HD + c4*16;
        const unsigned short* qp2 = qlo_g + hb + (size_t)(n0 + r_st)*HD + c4*16;
        uint4 h0 = *(const uint4*)qp,  h1 = *(const uint4*)(qp + 8);
        uint4 l0 = *(const uint4*)qp2, l1 = *(const uint4*)(qp2 + 8);
        *(uint4*)&qhi_s[cx0*8] = h0; *(uint4*)&qhi_s[cx1*8] = h1;
        *(uint4*)&qlo_s[cx0*8] = l0; *(uint4*)&qlo_s[cx1*8] = l1;
    }
    __syncthreads();
    bf16x8 qh[2], ql[2];
    #pragma unroll
    for (int h = 0; h < 2; h++) {
        qh[h] = *(bf16x8*)&qhi_s[((w*2 + h)*64 + lane)*8];
        ql[h] = *(bf16x8*)&qlo_s[((w*2 + h)*64 + lane)*8];
    }

    {
        const unsigned short* kp  = khi_g + hb + (size_t)r_st*HD + c4*16;
        const unsigned short* kp2 = klo_g + hb + (size_t)r_st*HD + c4*16;
        uint4 kh0 = *(const uint4*)kp,  kh1 = *(const uint4*)(kp + 8);
        uint4 kl0 = *(const uint4*)kp2, kl1 = *(const uint4*)(kp2 + 8);
        *(uint4*)&khi_s[0][cx0*8] = kh0; *(uint4*)&khi_s[0][cx1*8] = kh1;
        *(uint4*)&klo_s[0][cx0*8] = kl0; *(uint4*)&klo_s[0][cx1*8] = kl1;
    }
    __syncthreads();

    float* srow_base = s_g + ((size_t)bhl << 20);

    for (int mt = 0; mt < SEQ / 64; mt++) {
        const int cur = mt & 1, nxt = cur ^ 1;
        uint4 kh0, kh1, kl0, kl1;
        if (mt + 1 < SEQ / 64) {
            const unsigned short* kp  = khi_g + hb + (size_t)((mt+1)*64 + r_st)*HD + c4*16;
            const unsigned short* kp2 = klo_g + hb + (size_t)((mt+1)*64 + r_st)*HD + c4*16;
            kh0 = *(const uint4*)kp;  kh1 = *(const uint4*)(kp + 8);
            kl0 = *(const uint4*)kp2; kl1 = *(const uint4*)(kp2 + 8);
        }

        #pragma unroll
        for (int ct = 0; ct < 4; ct++) {
            f32x4v acc = {0.f, 0.f, 0.f, 0.f};
            #pragma unroll
            for (int h = 0; h < 2; h++) {
                bf16x8 kfh = *(bf16x8*)&khi_s[cur][((ct*2 + h)*64 + lane)*8];
                bf16x8 kfl = *(bf16x8*)&klo_s[cur][((ct*2 + h)*64 + lane)*8];
                acc = __builtin_amdgcn_mfma_f32_16x16x32_bf16(qh[h], kfh, acc, 0, 0, 0);
                acc = __builtin_amdgcn_mfma_f32_16x16x32_bf16(qh[h], kfl, acc, 0, 0, 0);
                acc = __builtin_amdgcn_mfma_f32_16x16x32_bf16(ql[h], kfh, acc, 0, 0, 0);
            }
            const int col  = mt*64 + ct*16 + (lane & 15);
            const int rowb = n0 + w*16 + (lane >> 4)*4;
            float* sp = srow_base + ((size_t)rowb << 10) + col;
            #pragma unroll
            for (int rg = 0; rg < 4; rg++)
                sp[(size_t)rg << 10] = acc[rg] * 0.125f;
        }

        if (mt + 1 < SEQ / 64) {
            *(uint4*)&khi_s[nxt][cx0*8] = kh0; *(uint4*)&khi_s[nxt][cx1*8] = kh1;
            *(uint4*)&klo_s[nxt][cx0*8] = kl0; *(uint4*)&klo_s[nxt][cx1*8] = kl1;
        }
        __syncthreads();
    }
}

// ============================================================
// Kernel B: per-row top-16 + sparse softmax + PV, 2 rows/wave.
// DS ops/round cut to 4 (ord-only reduce + ballot tie-break);
// xor1/xor2 via DPP (VALU), xor4/8/16 via ds_swizzle, xor32 via shfl.
// Packed u64 keys keep exact jax order; per-lane sorted top-4 cache
// + rare exact refill; streaming softmax/PV fused.
// ============================================================
__device__ __forceinline__ unsigned long long packkey(float f, int gidx) {
    unsigned u = __float_as_uint(f);
    unsigned o = u ^ ((unsigned)((int)u >> 31) | 0x80000000u);
    return ((unsigned long long)o << 32) | (unsigned)(~gidx);
}

struct TopCache { unsigned long long t0, t1, t2, t3; int cnt; };

__device__ __forceinline__ void cache_insert(TopCache& c, unsigned long long k) {
    bool b0 = k > c.t0, b1 = k > c.t1, b2 = k > c.t2, b3 = k > c.t3;
    c.t3 = b3 ? (b2 ? c.t2 : k) : c.t3;
    c.t2 = b2 ? (b1 ? c.t1 : k) : c.t2;
    c.t1 = b1 ? (b0 ? c.t0 : k) : c.t1;
    c.t0 = b0 ? k : c.t0;
}

__device__ __forceinline__ void cache_build(TopCache& c, const float* v, int gbase) {
    c.t0 = c.t1 = c.t2 = c.t3 = 0ull;
    #pragma unroll
    for (int j = 0; j < 16; j++) cache_insert(c, packkey(v[j], gbase + j));
    c.cnt = 4;
}

__device__ __forceinline__ void cache_pop_own(TopCache& c, bool own) {
    c.t0 = own ? c.t1 : c.t0;
    c.t1 = own ? c.t2 : c.t1;
    c.t2 = own ? c.t3 : c.t2;
    c.t3 = own ? 0ull : c.t3;
    c.cnt -= own;
}

// rebuild cache from retained values strictly below kw (extraction order
// is strictly decreasing, so remaining keys are exactly those < kw)
__device__ __forceinline__ void cache_refill(TopCache& c, const float* v,
                                             int gbase, unsigned long long kw) {
    c.t0 = c.t1 = c.t2 = c.t3 = 0ull;
    int cc = 0;
    #pragma unroll
    for (int j = 0; j < 16; j++) {
        unsigned long long k = packkey(v[j], gbase + j);
        if (k < kw) { cc++; cache_insert(c, k); }
    }
    c.cnt = cc > 4 ? 4 : cc;
}

__device__ __forceinline__ unsigned umax2(unsigned a, unsigned b) { return a > b ? a : b; }

// wave-wide max of 32-bit ord: 2 DPP (VALU) + 3 ds_swizzle + 1 shfl (DS)
__device__ __forceinline__ unsigned wave_max_ord(unsigned o) {
    unsigned p;
    p = (unsigned)__builtin_amdgcn_update_dpp(0, (int)o, 0xB1, 0xF, 0xF, true); o = umax2(o, p); // xor1 quad_perm[1,0,3,2]
    p = (unsigned)__builtin_amdgcn_update_dpp(0, (int)o, 0x4E, 0xF, 0xF, true); o = umax2(o, p); // xor2 quad_perm[2,3,0,1]
    p = (unsigned)__builtin_amdgcn_ds_swizzle((int)o, 0x101F); o = umax2(o, p);                  // xor4
    p = (unsigned)__builtin_amdgcn_ds_swizzle((int)o, 0x201F); o = umax2(o, p);                  // xor8
    p = (unsigned)__builtin_amdgcn_ds_swizzle((int)o, 0x401F); o = umax2(o, p);                  // xor16
    p = (unsigned)__shfl_xor((int)o, 32);                      o = umax2(o, p);                  // xor32
    return o;
}

__device__ __forceinline__ float ord_to_float(unsigned o) {
    return __uint_as_float(o ^ ((unsigned)((int)(~o) >> 31) | 0x80000000u));
}

__global__ __launch_bounds__(256) void topk_pv_kernel(
    const float* __restrict__ s_g, const float* __restrict__ v_ws,
    const float* __restrict__ vsum_ws,
    unsigned short* __restrict__ aohi, unsigned short* __restrict__ aolo, int bh0)
{
    const int lane = threadIdx.x & 63;
    const int wid  = (blockIdx.x * 256 + threadIdx.x) >> 6;   // 0..G*512-1
    const int bhl  = wid >> 9;
    const int pr   = wid & 511;
    const int nA   = pr * 2;
    const int bh   = bh0 + bhl;
    const int gbase = lane * 16;

    const float* srowA = s_g + ((size_t)bhl << 20) + ((size_t)nA << 10) + gbase;
    const float* srowB = srowA + SEQ;
    float vA[16], vB[16];
    #pragma unroll
    for (int i = 0; i < 4; i++) {
        float4 ta = *(const float4*)(srowA + i * 4);
        vA[i*4+0] = ta.x; vA[i*4+1] = ta.y; vA[i*4+2] = ta.z; vA[i*4+3] = ta.w;
        float4 tb = *(const float4*)(srowB + i * 4);
        vB[i*4+0] = tb.x; vB[i*4+1] = tb.y; vB[i*4+2] = tb.z; vB[i*4+3] = tb.w;
    }

    TopCache cA, cB;
    cache_build(cA, vA, gbase);
    cache_build(cB, vB, gbase);

    const float* vh = v_ws + ((size_t)bh << 16);
    const float vs = vsum_ws[(bh << 6) + lane];

    float mxA, eA, ZA, SA, mxB, eB, ZB, SB;

    // ---- round 0: establish row max -> streaming softmax state ----
    {
        unsigned oA = (unsigned)(cA.t0 >> 32);
        unsigned oB = (unsigned)(cB.t0 >> 32);
        unsigned mA = wave_max_ord(oA);
        unsigned mB = wave_max_ord(oB);
        unsigned long long blA = __ballot(oA == mA);
        unsigned long long blB = __ballot(oB == mB);
        int sA = __ffsll(blA) - 1;
        int sB = __ffsll(blB) - 1;
        unsigned loA = (unsigned)__builtin_amdgcn_readlane((int)(unsigned)cA.t0, sA);
        unsigned loB = (unsigned)__builtin_amdgcn_readlane((int)(unsigned)cB.t0, sB);
        float valA = ord_to_float(mA), valB = ord_to_float(mB);
        int idxA = (int)((~loA) & 1023u);
        int idxB = (int)((~loB) & 1023u);

        mxA = fmaxf(valA, 0.f); eA = __expf(-mxA);
        float wEA = __expf(valA - mxA);
        ZA = (float)(SEQ - TOPK) * eA + wEA;
        SA = (wEA - eA) * vh[((size_t)idxA << 6) + lane];

        mxB = fmaxf(valB, 0.f); eB = __expf(-mxB);
        float wEB = __expf(valB - mxB);
        ZB = (float)(SEQ - TOPK) * eB + wEB;
        SB = (wEB - eB) * vh[((size_t)idxB << 6) + lane];

        cache_pop_own(cA, lane == sA);    // cnt >= 3, no refill possible
        cache_pop_own(cB, lane == sB);
    }

    // ---- rounds 1..15 (two independent chains interleaved) ----
    #pragma unroll 1
    for (int t = 1; t < TOPK; t++) {
        unsigned oA = (unsigned)(cA.t0 >> 32);
        unsigned oB = (unsigned)(cB.t0 >> 32);
        unsigned mA = wave_max_ord(oA);
        unsigned mB = wave_max_ord(oB);
        unsigned long long blA = __ballot(oA == mA);
        unsigned long long blB = __ballot(oB == mB);
        int sA = __ffsll(blA) - 1;
        int sB = __ffsll(blB) - 1;
        unsigned loA = (unsigned)__builtin_amdgcn_readlane((int)(unsigned)cA.t0, sA);
        unsigned loB = (unsigned)__builtin_amdgcn_readlane((int)(unsigned)cB.t0, sB);
        float valA = ord_to_float(mA), valB = ord_to_float(mB);
        int idxA = (int)((~loA) & 1023u);
        int idxB = (int)((~loB) & 1023u);

        float wEA = __expf(valA - mxA);
        ZA += wEA;
        SA = fmaf(wEA - eA, vh[((size_t)idxA << 6) + lane], SA);

        float wEB = __expf(valB - mxB);
        ZB += wEB;
        SB = fmaf(wEB - eB, vh[((size_t)idxB << 6) + lane], SB);

        cache_pop_own(cA, lane == sA);
        cache_pop_own(cB, lane == sB);

        if (cA.cnt == 0 && t < TOPK - 1) {
            unsigned long long kwA = ((unsigned long long)mA << 32) | loA;
            cache_refill(cA, vA, gbase, kwA);
        }
        if (cB.cnt == 0 && t < TOPK - 1) {
            unsigned long long kwB = ((unsigned long long)mB << 32) | loB;
            cache_refill(cB, vB, gbase, kwB);
        }
    }

    float accA = (eA * vs + SA) / ZA;
    float accB = (eB * vs + SB) / ZB;

    const int b = bh >> 3, hh = bh & 7;
    size_t oA = (((size_t)b << 10) + nA) * CDIM + (hh << 6) + lane;
    unsigned short sh, sl;
    bf16split(accA, sh, sl);
    aohi[oA] = sh; aolo[oA] = sl;
    bf16split(accB, sh, sl);
    aohi[oA + CDIM] = sh; aolo[oA + CDIM] = sl;
}

// ============================================================
// Kernel 4: output projection via MFMA: out = ao @ Wp + bp
// ============================================================
__global__ __launch_bounds__(256, 2) void proj_mfma_kernel(
    const unsigned short* __restrict__ aohi, const unsigned short* __restrict__ aolo,
    const unsigned short* __restrict__ wpThi, const unsigned short* __restrict__ wpTlo,
    const float* __restrict__ bp, float* __restrict__ out)
{
    const int tid = threadIdx.x, lane = tid & 63, w = tid >> 6;
    const int row0 = blockIdx.x * 128, col0 = blockIdx.y * 128;

    f32x4v acc[4][4];
    mfma_gemm_core(aohi, aolo, wpThi, wpTlo, row0, col0, lane, w, acc);

    const int wr = w >> 1, wc = w & 1;
    #pragma unroll
    for (int i = 0; i < 4; i++) {
        int rG = row0 + (wr*4 + i) * 16 + (lane & 15);
        #pragma unroll
        for (int j = 0; j < 4; j++) {
            int cG = col0 + (wc*4 + j) * 16 + (lane >> 4) * 4;
            float4 b4 = *(const float4*)(bp + cG);
            float4 val;
            val.x = acc[i][j][0] + b4.x;
            val.y = acc[i][j][1] + b4.y;
            val.z = acc[i][j][2] + b4.z;
            val.w = acc[i][j][3] + b4.w;
            *(float4*)(out + (size_t)rG * CDIM + cG) = val;
        }
    }
}

// ============================================================
extern "C" void kernel_launch(void* const* d_in, const int* in_sizes, int n_in,
                              void* d_out, int out_size, void* d_ws, size_t ws_size,
                              hipStream_t stream)
{
    const float* x   = (const float*)d_in[0];
    const float* Wq  = (const float*)d_in[1];
    const float* bq  = (const float*)d_in[2];
    const float* Wkv = (const float*)d_in[3];
    const float* bkv = (const float*)d_in[4];
    const float* Wp  = (const float*)d_in[5];
    const float* bp  = (const float*)d_in[6];
    float* out = (float*)d_out;

    const size_t HSZ = (size_t)BATCH * HEADS * SEQ * HD;   // 4,194,304
    float* ws    = (float*)d_ws;
    float* v_ws  = ws;
    float* vs_ws = ws + HSZ;
    unsigned short* qhi_g = (unsigned short*)(ws + HSZ + 4096);
    unsigned short* qlo_g = qhi_g + HSZ;
    unsigned short* khi_g = qhi_g + 2 * HSZ;
    unsigned short* klo_g = qhi_g + 3 * HSZ;
    unsigned short* xhi_g = qhi_g + 4 * HSZ;   // aliased: ao hi plane after qkv
    unsigned short* xlo_g = qhi_g + 5 * HSZ;   // aliased: ao lo plane after qkv
    unsigned short* bThi  = qhi_g + 6 * HSZ;
    unsigned short* bTlo  = bThi + (size_t)1536 * 512;
    unsigned short* wpThi = bThi + (size_t)2 * 1536 * 512;
    unsigned short* wpTlo = wpThi + (size_t)512 * 512;

    const size_t plane_us = 6 * HSZ + (size_t)2 * 1536 * 512 + (size_t)2 * 512 * 512;
    const size_t base_fl  = HSZ + 4096 + plane_us / 2;
    float* s_g = ws + base_fl;

    const size_t avail_fl = (ws_size / 4 > base_fl) ? (ws_size / 4 - base_fl) : 0;
    // G capped at 32: 134 MB score working set fits L3 together with the
    // q/k/v planes, keeping the score write->read round-trip mostly in L3.
    int G = 32;
    while (G > 1 && (size_t)G * SEQ * SEQ > avail_fl) G >>= 1;

    split_x_kernel<<<dim3((MTOT * CDIM) / (256 * 4)), 256, 0, stream>>>(x, xhi_g, xlo_g);
    split_wT_kernel<<<dim3(32, 8), 256, 0, stream>>>(Wq, Wkv, Wp, bThi, bTlo, wpThi, wpTlo);
    qkv_mfma_kernel<<<dim3(MTOT / 128, 12), 256, 0, stream>>>(
        xhi_g, xlo_g, bThi, bTlo, bq, bkv, qhi_g, qlo_g, khi_g, klo_g, v_ws);
    vsum_kernel<<<BATCH * HEADS, 256, 0, stream>>>(v_ws, vs_ws);
    for (int bh0 = 0; bh0 < BATCH * HEADS; bh0 += G) {
        score_kernel<<<dim3(SEQ / 64, G), 256, 0, stream>>>(
            qhi_g, qlo_g, khi_g, klo_g, s_g, bh0);
        topk_pv_kernel<<<dim3(G * (SEQ / 8)), 256, 0, stream>>>(
            s_g, v_ws, vs_ws, xhi_g, xlo_g, bh0);
    }
    proj_mfma_kernel<<<dim3(MTOT / 128, CDIM / 128), 256, 0, stream>>>(
        xhi_g, xlo_g, wpThi, wpTlo, bp, out);
}

// Round 8
// 385.905 us; speedup vs baseline: 1.0177x; 1.0177x over previous
//
#include <hip/hip_runtime.h>
#include <float.h>

#define BATCH 8
#define SEQ   1024
#define CDIM  512
#define HEADS 8
#define HD    64
#define TOPK  16
#define MTOT  (BATCH*SEQ)   // 8192

typedef short bf16x8 __attribute__((ext_vector_type(8)));
typedef float f32x4v __attribute__((ext_vector_type(4)));
typedef unsigned int __attribute__((address_space(1))) guint;
typedef unsigned int __attribute__((address_space(3))) luint;

// round-to-nearest bf16 split: f = hi + lo, each bf16; |err| ~ 2^-17 |f|
__device__ inline void bf16split(float f, unsigned short& h, unsigned short& l) {
    unsigned u = __float_as_uint(f);
    unsigned hr = (u + 0x7fffu + ((u >> 16) & 1u)) >> 16;
    h = (unsigned short)hr;
    float rest = f - __uint_as_float(hr << 16);
    unsigned v = __float_as_uint(rest);
    l = (unsigned short)((v + 0x7fffu + ((v >> 16) & 1u)) >> 16);
}

// ============================================================
// Prep 1: split x into bf16 hi/lo planes (row-major [8192][512])
// ============================================================
__global__ __launch_bounds__(256) void split_x_kernel(
    const float* __restrict__ x,
    unsigned short* __restrict__ xhi, unsigned short* __restrict__ xlo)
{
    size_t i = ((size_t)blockIdx.x * 256 + threadIdx.x) * 4;
    float4 v = *(const float4*)(x + i);
    ushort4 h, l;
    bf16split(v.x, h.x, l.x); bf16split(v.y, h.y, l.y);
    bf16split(v.z, h.z, l.z); bf16split(v.w, h.w, l.w);
    *(ushort4*)(xhi + i) = h;
    *(ushort4*)(xlo + i) = l;
}

// ============================================================
// Prep 2: transpose + split weights.
//   BT  [1536][512] = concat(Wq, Wkv) columns as rows (bf16 hi/lo)
//   WpT [512][512]  = Wp columns as rows (bf16 hi/lo)
// ============================================================
__global__ __launch_bounds__(256) void split_wT_kernel(
    const float* __restrict__ Wq, const float* __restrict__ Wkv,
    const float* __restrict__ Wp,
    unsigned short* __restrict__ bThi, unsigned short* __restrict__ bTlo,
    unsigned short* __restrict__ wpThi, unsigned short* __restrict__ wpTlo)
{
    __shared__ float tile[64][65];
    const int ct = blockIdx.x, k0 = blockIdx.y * 64, t = threadIdx.x;
    const float* src; int ld, sc0, dr0;
    unsigned short *dhi, *dlo;
    if (ct < 8)       { src = Wq;  ld = CDIM;     sc0 = ct * 64;        dr0 = ct * 64;              dhi = bThi;  dlo = bTlo;  }
    else if (ct < 24) { src = Wkv; ld = 2 * CDIM; sc0 = (ct - 8) * 64;  dr0 = CDIM + (ct - 8) * 64; dhi = bThi;  dlo = bTlo;  }
    else              { src = Wp;  ld = CDIM;     sc0 = (ct - 24) * 64; dr0 = (ct - 24) * 64;       dhi = wpThi; dlo = wpTlo; }

    #pragma unroll
    for (int i = 0; i < 4; i++) {
        int f = t + i * 256;          // 0..1023
        int r = f >> 4, c4 = f & 15;  // k-row, col-segment
        float4 v = *(const float4*)(src + (size_t)(k0 + r) * ld + sc0 + c4 * 4);
        tile[c4*4+0][r] = v.x; tile[c4*4+1][r] = v.y;
        tile[c4*4+2][r] = v.z; tile[c4*4+3][r] = v.w;
    }
    __syncthreads();
    #pragma unroll
    for (int i = 0; i < 2; i++) {
        int f = t + i * 256;          // 0..511
        int c = f >> 3, ko = f & 7;
        const float* tp = &tile[c][ko * 8];
        ushort4 h0, l0, h1, l1;
        bf16split(tp[0], h0.x, l0.x); bf16split(tp[1], h0.y, l0.y);
        bf16split(tp[2], h0.z, l0.z); bf16split(tp[3], h0.w, l0.w);
        bf16split(tp[4], h1.x, l1.x); bf16split(tp[5], h1.y, l1.y);
        bf16split(tp[6], h1.z, l1.z); bf16split(tp[7], h1.w, l1.w);
        size_t o = (size_t)(dr0 + c) * CDIM + k0 + ko * 8;
        *(ushort4*)(dhi + o)     = h0; *(ushort4*)(dhi + o + 4) = h1;
        *(ushort4*)(dlo + o)     = l0; *(ushort4*)(dlo + o + 4) = l1;
    }
}

// ============================================================
// Shared MFMA GEMM core: C[128x128] = A[128xK] * B^T[128xK]^T, K=512,
// split-bf16 3-product (hi*hi + hi*lo + lo*hi), fp32 accumulate.
// REVERTED to round-6 2-phase double-buffered LDS pipeline (67.6 us
// measured) — round-7's LDS-free register pipeline regressed (105 us:
// depth-1 reg dbuf can't hide L2 latency; lost intra-block sharing).
// ============================================================
__device__ __forceinline__ void mfma_gemm_core(
    const unsigned short* __restrict__ ahi, const unsigned short* __restrict__ alo,
    const unsigned short* __restrict__ bhi, const unsigned short* __restrict__ blo,
    int row0, int col0, int lane, int w, f32x4v acc[4][4])
{
    __shared__ __align__(16) unsigned short ah_s[2][4096], al_s[2][4096];
    __shared__ __align__(16) unsigned short bh_s[2][4096], bl_s[2][4096];

    const unsigned short* gsrc;
    unsigned short* lb[2];
    if (w == 0)      { gsrc = ahi; lb[0] = ah_s[0]; lb[1] = ah_s[1]; }
    else if (w == 1) { gsrc = alo; lb[0] = al_s[0]; lb[1] = al_s[1]; }
    else if (w == 2) { gsrc = bhi; lb[0] = bh_s[0]; lb[1] = bh_s[1]; }
    else             { gsrc = blo; lb[0] = bl_s[0]; lb[1] = bl_s[1]; }
    const int tile0 = (w < 2) ? row0 : col0;
    // per-lane source: row tile0 + c*16 + (lane&15), k-octet (lane>>4)
    const size_t goff = (size_t)(tile0 + (lane & 15)) * CDIM + (lane >> 4) * 8;
    const int wr = w >> 1, wc = w & 1;

    #pragma unroll
    for (int i = 0; i < 4; i++)
        #pragma unroll
        for (int j = 0; j < 4; j++)
            acc[i][j] = (f32x4v){0.f, 0.f, 0.f, 0.f};

    // prologue: stage K-tile 0 into buffer 0, drain, barrier
    #pragma unroll
    for (int c = 0; c < 8; c++)
        __builtin_amdgcn_global_load_lds(
            (const guint*)(gsrc + goff + (size_t)c * 16 * CDIM),
            (luint*)(lb[0] + c * 512), 16, 0, 0);
    asm volatile("s_waitcnt vmcnt(0)" ::: "memory");
    __builtin_amdgcn_s_barrier();

    int cur = 0;
    for (int kt = 0; kt < CDIM; kt += 32) {
        // issue next tile's stage into the other buffer (overlaps compute)
        if (kt + 32 < CDIM) {
            unsigned short* ln = lb[cur ^ 1];
            #pragma unroll
            for (int c = 0; c < 8; c++)
                __builtin_amdgcn_global_load_lds(
                    (const guint*)(gsrc + goff + kt + 32 + (size_t)c * 16 * CDIM),
                    (luint*)(ln + c * 512), 16, 0, 0);
        }

        // compute current buffer
        const unsigned short* ah = ah_s[cur];
        const unsigned short* al = al_s[cur];
        const unsigned short* bh = bh_s[cur];
        const unsigned short* bl = bl_s[cur];
        bf16x8 afh[4], afl[4], bfh[4], bfl[4];
        #pragma unroll
        for (int i = 0; i < 4; i++) {
            afh[i] = *(const bf16x8*)&ah[(((wr*4 + i) * 64) + lane) * 8];
            afl[i] = *(const bf16x8*)&al[(((wr*4 + i) * 64) + lane) * 8];
            bfh[i] = *(const bf16x8*)&bh[(((wc*4 + i) * 64) + lane) * 8];
            bfl[i] = *(const bf16x8*)&bl[(((wc*4 + i) * 64) + lane) * 8];
        }
        #pragma unroll
        for (int i = 0; i < 4; i++)
            #pragma unroll
            for (int j = 0; j < 4; j++) {
                acc[i][j] = __builtin_amdgcn_mfma_f32_16x16x32_bf16(bfh[j], afh[i], acc[i][j], 0, 0, 0);
                acc[i][j] = __builtin_amdgcn_mfma_f32_16x16x32_bf16(bfh[j], afl[i], acc[i][j], 0, 0, 0);
                acc[i][j] = __builtin_amdgcn_mfma_f32_16x16x32_bf16(bfl[j], afh[i], acc[i][j], 0, 0, 0);
            }

        // pin order, wait prefetch completion, barrier; swap buffers
        __builtin_amdgcn_sched_barrier(0);
        asm volatile("s_waitcnt vmcnt(0)" ::: "memory");
        __builtin_amdgcn_s_barrier();
        cur ^= 1;
    }
}

// ============================================================
// Kernel 1: QKV projection via MFMA.
// ============================================================
__global__ __launch_bounds__(256) void qkv_mfma_kernel(
    const unsigned short* __restrict__ xhi, const unsigned short* __restrict__ xlo,
    const unsigned short* __restrict__ bThi, const unsigned short* __restrict__ bTlo,
    const float* __restrict__ bq, const float* __restrict__ bkv,
    unsigned short* __restrict__ qhi_g, unsigned short* __restrict__ qlo_g,
    unsigned short* __restrict__ khi_g, unsigned short* __restrict__ klo_g,
    float* __restrict__ v_ws)
{
    const int tid = threadIdx.x, lane = tid & 63, w = tid >> 6;
    const int row0 = blockIdx.x * 128, col0 = blockIdx.y * 128;

    f32x4v acc[4][4];
    mfma_gemm_core(xhi, xlo, bThi, bTlo, row0, col0, lane, w, acc);

    const int wr = w >> 1, wc = w & 1;
    const bool isq = (col0 < CDIM);
    #pragma unroll
    for (int i = 0; i < 4; i++) {
        int rG = row0 + (wr*4 + i) * 16 + (lane & 15);
        int bb = rG >> 10, nn = rG & (SEQ - 1);
        #pragma unroll
        for (int j = 0; j < 4; j++) {
            int cG = col0 + (wc*4 + j) * 16 + (lane >> 4) * 4;
            float4 bias4 = isq ? *(const float4*)(bq + cG)
                               : *(const float4*)(bkv + cG - CDIM);
            float4 val;
            val.x = acc[i][j][0] + bias4.x;
            val.y = acc[i][j][1] + bias4.y;
            val.z = acc[i][j][2] + bias4.z;
            val.w = acc[i][j][3] + bias4.w;
            if (isq) {
                val.x = fmaxf(val.x, 0.f); val.y = fmaxf(val.y, 0.f);
                val.z = fmaxf(val.z, 0.f); val.w = fmaxf(val.w, 0.f);
                int hq = cG >> 6, d = cG & 63;
                size_t base = (((size_t)bb * HEADS + hq) * SEQ + nn) * HD + d;
                ushort4 hv, lv;
                bf16split(val.x, hv.x, lv.x); bf16split(val.y, hv.y, lv.y);
                bf16split(val.z, hv.z, lv.z); bf16split(val.w, hv.w, lv.w);
                *(ushort4*)(qhi_g + base) = hv;
                *(ushort4*)(qlo_g + base) = lv;
            } else {
                int c2 = cG - CDIM;
                int t = c2 >> 9, hq = (c2 >> 6) & 7, d = c2 & 63;
                size_t base = (((size_t)bb * HEADS + hq) * SEQ + nn) * HD + d;
                if (t == 0) {
                    ushort4 hv, lv;
                    bf16split(val.x, hv.x, lv.x); bf16split(val.y, hv.y, lv.y);
                    bf16split(val.z, hv.z, lv.z); bf16split(val.w, hv.w, lv.w);
                    *(ushort4*)(khi_g + base) = hv;
                    *(ushort4*)(klo_g + base) = lv;
                } else {
                    *(float4*)(v_ws + base) = val;
                }
            }
        }
    }
}

// ============================================================
// Kernel 2: per-(b,h) column sum of V  -> vsum[bh][64]
// ============================================================
__global__ __launch_bounds__(256) void vsum_kernel(
    const float* __restrict__ v_ws, float* __restrict__ vsum_ws)
{
    __shared__ float red[4][HD];
    const int bh = blockIdx.x;
    const int d  = threadIdx.x & 63;
    const int sl = threadIdx.x >> 6;
    const float* vh = v_ws + (size_t)bh * SEQ * HD;
    float s = 0.f;
    for (int m = sl * 256; m < (sl + 1) * 256; m++) s += vh[(size_t)m * HD + d];
    red[sl][d] = s;
    __syncthreads();
    if (threadIdx.x < HD)
        vsum_ws[(size_t)bh * HD + d] = red[0][d] + red[1][d] + red[2][d] + red[3][d];
}

// ============================================================
// Kernel A: MFMA split-bf16 scores -> global fp32 [bhl][1024][1024]
// (scaled by D^-0.5). Double-buffered K tiles.
// ============================================================
__global__ __launch_bounds__(256) void score_kernel(
    const unsigned short* __restrict__ qhi_g, const unsigned short* __restrict__ qlo_g,
    const unsigned short* __restrict__ khi_g, const unsigned short* __restrict__ klo_g,
    float* __restrict__ s_g, int bh0)
{
    __shared__ __align__(16) short qhi_s[4096], qlo_s[4096];
    __shared__ __align__(16) short khi_s[2][4096], klo_s[2][4096];

    const int bhl = blockIdx.y;
    const int bh  = bh0 + bhl;
    const int n0  = blockIdx.x * 64;
    const int tid = threadIdx.x;
    const int lane = tid & 63, w = tid >> 6;
    const int r_st = tid >> 2, c4 = tid & 3;
    const size_t hb = (size_t)bh * SEQ * HD;

    const int s0 = c4 * 2, s1 = s0 + 1;
    const int cx0 = ((r_st >> 4)*2 + (s0 >> 2))*64 + (s0 & 3)*16 + (r_st & 15);
    const int cx1 = ((r_st >> 4)*2 + (s1 >> 2))*64 + (s1 & 3)*16 + (r_st & 15);

    {
        const unsigned short* qp  = qhi_g + hb + (size_t)(n0 + r_st)*HD + c4*16;
        const unsigned short* qp2 = qlo_g + hb + (size_t)(n0 + r_st)*HD + c4*16;
        uint4 h0 = *(const uint4*)qp,  h1 = *(const uint4*)(qp + 8);
        uint4 l0 = *(const uint4*)qp2, l1 = *(const uint4*)(qp2 + 8);
        *(uint4*)&qhi_s[cx0*8] = h0; *(uint4*)&qhi_s[cx1*8] = h1;
        *(uint4*)&qlo_s[cx0*8] = l0; *(uint4*)&qlo_s[cx1*8] = l1;
    }
    __syncthreads();
    bf16x8 qh[2], ql[2];
    #pragma unroll
    for (int h = 0; h < 2; h++) {
        qh[h] = *(bf16x8*)&qhi_s[((w*2 + h)*64 + lane)*8];
        ql[h] = *(bf16x8*)&qlo_s[((w*2 + h)*64 + lane)*8];
    }

    {
        const unsigned short* kp  = khi_g + hb + (size_t)r_st*HD + c4*16;
        const unsigned short* kp2 = klo_g + hb + (size_t)r_st*HD + c4*16;
        uint4 kh0 = *(const uint4*)kp,  kh1 = *(const uint4*)(kp + 8);
        uint4 kl0 = *(const uint4*)kp2, kl1 = *(const uint4*)(kp2 + 8);
        *(uint4*)&khi_s[0][cx0*8] = kh0; *(uint4*)&khi_s[0][cx1*8] = kh1;
        *(uint4*)&klo_s[0][cx0*8] = kl0; *(uint4*)&klo_s[0][cx1*8] = kl1;
    }
    __syncthreads();

    float* srow_base = s_g + ((size_t)bhl << 20);

    for (int mt = 0; mt < SEQ / 64; mt++) {
        const int cur = mt & 1, nxt = cur ^ 1;
        uint4 kh0, kh1, kl0, kl1;
        if (mt + 1 < SEQ / 64) {
            const unsigned short* kp  = khi_g + hb + (size_t)((mt+1)*64 + r_st)*HD + c4*16;
            const unsigned short* kp2 = klo_g + hb + (size_t)((mt+1)*64 + r_st)*HD + c4*16;
            kh0 = *(const uint4*)kp;  kh1 = *(const uint4*)(kp + 8);
            kl0 = *(const uint4*)kp2; kl1 = *(const uint4*)(kp2 + 8);
        }

        #pragma unroll
        for (int ct = 0; ct < 4; ct++) {
            f32x4v acc = {0.f, 0.f, 0.f, 0.f};
            #pragma unroll
            for (int h = 0; h < 2; h++) {
                bf16x8 kfh = *(bf16x8*)&khi_s[cur][((ct*2 + h)*64 + lane)*8];
                bf16x8 kfl = *(bf16x8*)&klo_s[cur][((ct*2 + h)*64 + lane)*8];
                acc = __builtin_amdgcn_mfma_f32_16x16x32_bf16(qh[h], kfh, acc, 0, 0, 0);
                acc = __builtin_amdgcn_mfma_f32_16x16x32_bf16(qh[h], kfl, acc, 0, 0, 0);
                acc = __builtin_amdgcn_mfma_f32_16x16x32_bf16(ql[h], kfh, acc, 0, 0, 0);
            }
            const int col  = mt*64 + ct*16 + (lane & 15);
            const int rowb = n0 + w*16 + (lane >> 4)*4;
            float* sp = srow_base + ((size_t)rowb << 10) + col;
            #pragma unroll
            for (int rg = 0; rg < 4; rg++)
                sp[(size_t)rg << 10] = acc[rg] * 0.125f;
        }

        if (mt + 1 < SEQ / 64) {
            *(uint4*)&khi_s[nxt][cx0*8] = kh0; *(uint4*)&khi_s[nxt][cx1*8] = kh1;
            *(uint4*)&klo_s[nxt][cx0*8] = kl0; *(uint4*)&klo_s[nxt][cx1*8] = kl1;
        }
        __syncthreads();
    }
}

// ============================================================
// Kernel B: per-row top-16 + sparse softmax + PV, NOW 4 rows/wave.
// Round-5 cut DS ops/round to 4/row; remaining cost is the 6-step
// dependent swizzle chain latency per round (DS-throughput model says
// ~20us but kernel runs ~70us -> latency-bound). 4 independent row
// chains per wave interleave to hide it. VGPR ~150 -> 3 waves/SIMD,
// 12 waves/CU; G*256 waves total = 32/CU available.
// Packed u64 keys keep exact jax order; per-lane sorted top-4 cache
// + rare exact refill; streaming softmax/PV fused.
// ============================================================
__device__ __forceinline__ unsigned long long packkey(float f, int gidx) {
    unsigned u = __float_as_uint(f);
    unsigned o = u ^ ((unsigned)((int)u >> 31) | 0x80000000u);
    return ((unsigned long long)o << 32) | (unsigned)(~gidx);
}

struct TopCache { unsigned long long t0, t1, t2, t3; int cnt; };

__device__ __forceinline__ void cache_insert(TopCache& c, unsigned long long k) {
    bool b0 = k > c.t0, b1 = k > c.t1, b2 = k > c.t2, b3 = k > c.t3;
    c.t3 = b3 ? (b2 ? c.t2 : k) : c.t3;
    c.t2 = b2 ? (b1 ? c.t1 : k) : c.t2;
    c.t1 = b1 ? (b0 ? c.t0 : k) : c.t1;
    c.t0 = b0 ? k : c.t0;
}

__device__ __forceinline__ void cache_build(TopCache& c, const float* v, int gbase) {
    c.t0 = c.t1 = c.t2 = c.t3 = 0ull;
    #pragma unroll
    for (int j = 0; j < 16; j++) cache_insert(c, packkey(v[j], gbase + j));
    c.cnt = 4;
}

__device__ __forceinline__ void cache_pop_own(TopCache& c, bool own) {
    c.t0 = own ? c.t1 : c.t0;
    c.t1 = own ? c.t2 : c.t1;
    c.t2 = own ? c.t3 : c.t2;
    c.t3 = own ? 0ull : c.t3;
    c.cnt -= own;
}

// rebuild cache from retained values strictly below kw (extraction order
// is strictly decreasing, so remaining keys are exactly those < kw)
__device__ __forceinline__ void cache_refill(TopCache& c, const float* v,
                                             int gbase, unsigned long long kw) {
    c.t0 = c.t1 = c.t2 = c.t3 = 0ull;
    int cc = 0;
    #pragma unroll
    for (int j = 0; j < 16; j++) {
        unsigned long long k = packkey(v[j], gbase + j);
        if (k < kw) { cc++; cache_insert(c, k); }
    }
    c.cnt = cc > 4 ? 4 : cc;
}

__device__ __forceinline__ unsigned umax2(unsigned a, unsigned b) { return a > b ? a : b; }

// wave-wide max of 32-bit ord: 2 DPP (VALU) + 3 ds_swizzle + 1 shfl (DS)
__device__ __forceinline__ unsigned wave_max_ord(unsigned o) {
    unsigned p;
    p = (unsigned)__builtin_amdgcn_update_dpp(0, (int)o, 0xB1, 0xF, 0xF, true); o = umax2(o, p); // xor1 quad_perm[1,0,3,2]
    p = (unsigned)__builtin_amdgcn_update_dpp(0, (int)o, 0x4E, 0xF, 0xF, true); o = umax2(o, p); // xor2 quad_perm[2,3,0,1]
    p = (unsigned)__builtin_amdgcn_ds_swizzle((int)o, 0x101F); o = umax2(o, p);                  // xor4
    p = (unsigned)__builtin_amdgcn_ds_swizzle((int)o, 0x201F); o = umax2(o, p);                  // xor8
    p = (unsigned)__builtin_amdgcn_ds_swizzle((int)o, 0x401F); o = umax2(o, p);                  // xor16
    p = (unsigned)__shfl_xor((int)o, 32);                      o = umax2(o, p);                  // xor32
    return o;
}

__device__ __forceinline__ float ord_to_float(unsigned o) {
    return __uint_as_float(o ^ ((unsigned)((int)(~o) >> 31) | 0x80000000u));
}

__global__ __launch_bounds__(256) void topk_pv_kernel(
    const float* __restrict__ s_g, const float* __restrict__ v_ws,
    const float* __restrict__ vsum_ws,
    unsigned short* __restrict__ aohi, unsigned short* __restrict__ aolo, int bh0)
{
    const int lane = threadIdx.x & 63;
    const int wid  = (blockIdx.x * 256 + threadIdx.x) >> 6;   // 0..G*256-1
    const int bhl  = wid >> 8;          // 256 waves per bh (4 rows each)
    const int pr   = wid & 255;
    const int n0   = pr * 4;
    const int bh   = bh0 + bhl;
    const int gbase = lane * 16;

    float v[4][16];
    const float* srow0 = s_g + ((size_t)bhl << 20) + ((size_t)n0 << 10) + gbase;
    #pragma unroll
    for (int r = 0; r < 4; r++) {
        #pragma unroll
        for (int i = 0; i < 4; i++) {
            float4 t4 = *(const float4*)(srow0 + r * SEQ + i * 4);
            v[r][i*4+0] = t4.x; v[r][i*4+1] = t4.y;
            v[r][i*4+2] = t4.z; v[r][i*4+3] = t4.w;
        }
    }

    TopCache c[4];
    #pragma unroll
    for (int r = 0; r < 4; r++) cache_build(c[r], v[r], gbase);

    const float* vh = v_ws + ((size_t)bh << 16);
    const float vs = vsum_ws[(bh << 6) + lane];

    float mx[4], e[4], Z[4], S[4];

    // ---- round 0: establish row max -> streaming softmax state ----
    {
        unsigned m[4]; int sl4[4]; unsigned lo[4];
        #pragma unroll
        for (int r = 0; r < 4; r++) m[r] = wave_max_ord((unsigned)(c[r].t0 >> 32));
        #pragma unroll
        for (int r = 0; r < 4; r++) {
            unsigned long long bl = __ballot((unsigned)(c[r].t0 >> 32) == m[r]);
            sl4[r] = __ffsll(bl) - 1;
        }
        #pragma unroll
        for (int r = 0; r < 4; r++)
            lo[r] = (unsigned)__builtin_amdgcn_readlane((int)(unsigned)c[r].t0, sl4[r]);
        #pragma unroll
        for (int r = 0; r < 4; r++) {
            float val = ord_to_float(m[r]);
            int idx = (int)((~lo[r]) & 1023u);
            mx[r] = fmaxf(val, 0.f); e[r] = __expf(-mx[r]);
            float wE = __expf(val - mx[r]);
            Z[r] = (float)(SEQ - TOPK) * e[r] + wE;
            S[r] = (wE - e[r]) * vh[((size_t)idx << 6) + lane];
            cache_pop_own(c[r], lane == sl4[r]);   // cnt >= 3, no refill possible
        }
    }

    // ---- rounds 1..15 (four independent chains interleaved) ----
    #pragma unroll 1
    for (int t = 1; t < TOPK; t++) {
        unsigned m[4]; int sl4[4]; unsigned lo[4];
        #pragma unroll
        for (int r = 0; r < 4; r++) m[r] = wave_max_ord((unsigned)(c[r].t0 >> 32));
        #pragma unroll
        for (int r = 0; r < 4; r++) {
            unsigned long long bl = __ballot((unsigned)(c[r].t0 >> 32) == m[r]);
            sl4[r] = __ffsll(bl) - 1;
        }
        #pragma unroll
        for (int r = 0; r < 4; r++)
            lo[r] = (unsigned)__builtin_amdgcn_readlane((int)(unsigned)c[r].t0, sl4[r]);
        #pragma unroll
        for (int r = 0; r < 4; r++) {
            float val = ord_to_float(m[r]);
            int idx = (int)((~lo[r]) & 1023u);
            float wE = __expf(val - mx[r]);
            Z[r] += wE;
            S[r] = fmaf(wE - e[r], vh[((size_t)idx << 6) + lane], S[r]);
            cache_pop_own(c[r], lane == sl4[r]);
            if (c[r].cnt == 0 && t < TOPK - 1) {
                unsigned long long kw = ((unsigned long long)m[r] << 32) | lo[r];
                cache_refill(c[r], v[r], gbase, kw);
            }
        }
    }

    const int b = bh >> 3, hh = bh & 7;
    size_t o0 = (((size_t)b << 10) + n0) * CDIM + (hh << 6) + lane;
    #pragma unroll
    for (int r = 0; r < 4; r++) {
        float acc = (e[r] * vs + S[r]) / Z[r];
        unsigned short sh, sl;
        bf16split(acc, sh, sl);
        aohi[o0 + (size_t)r * CDIM] = sh;
        aolo[o0 + (size_t)r * CDIM] = sl;
    }
}

// ============================================================
// Kernel 4: output projection via MFMA: out = ao @ Wp + bp
// ============================================================
__global__ __launch_bounds__(256) void proj_mfma_kernel(
    const unsigned short* __restrict__ aohi, const unsigned short* __restrict__ aolo,
    const unsigned short* __restrict__ wpThi, const unsigned short* __restrict__ wpTlo,
    const float* __restrict__ bp, float* __restrict__ out)
{
    const int tid = threadIdx.x, lane = tid & 63, w = tid >> 6;
    const int row0 = blockIdx.x * 128, col0 = blockIdx.y * 128;

    f32x4v acc[4][4];
    mfma_gemm_core(aohi, aolo, wpThi, wpTlo, row0, col0, lane, w, acc);

    const int wr = w >> 1, wc = w & 1;
    #pragma unroll
    for (int i = 0; i < 4; i++) {
        int rG = row0 + (wr*4 + i) * 16 + (lane & 15);
        #pragma unroll
        for (int j = 0; j < 4; j++) {
            int cG = col0 + (wc*4 + j) * 16 + (lane >> 4) * 4;
            float4 b4 = *(const float4*)(bp + cG);
            float4 val;
            val.x = acc[i][j][0] + b4.x;
            val.y = acc[i][j][1] + b4.y;
            val.z = acc[i][j][2] + b4.z;
            val.w = acc[i][j][3] + b4.w;
            *(float4*)(out + (size_t)rG * CDIM + cG) = val;
        }
    }
}

// ============================================================
extern "C" void kernel_launch(void* const* d_in, const int* in_sizes, int n_in,
                              void* d_out, int out_size, void* d_ws, size_t ws_size,
                              hipStream_t stream)
{
    const float* x   = (const float*)d_in[0];
    const float* Wq  = (const float*)d_in[1];
    const float* bq  = (const float*)d_in[2];
    const float* Wkv = (const float*)d_in[3];
    const float* bkv = (const float*)d_in[4];
    const float* Wp  = (const float*)d_in[5];
    const float* bp  = (const float*)d_in[6];
    float* out = (float*)d_out;

    const size_t HSZ = (size_t)BATCH * HEADS * SEQ * HD;   // 4,194,304
    float* ws    = (float*)d_ws;
    float* v_ws  = ws;
    float* vs_ws = ws + HSZ;
    unsigned short* qhi_g = (unsigned short*)(ws + HSZ + 4096);
    unsigned short* qlo_g = qhi_g + HSZ;
    unsigned short* khi_g = qhi_g + 2 * HSZ;
    unsigned short* klo_g = qhi_g + 3 * HSZ;
    unsigned short* xhi_g = qhi_g + 4 * HSZ;   // aliased: ao hi plane after qkv
    unsigned short* xlo_g = qhi_g + 5 * HSZ;   // aliased: ao lo plane after qkv
    unsigned short* bThi  = qhi_g + 6 * HSZ;
    unsigned short* bTlo  = bThi + (size_t)1536 * 512;
    unsigned short* wpThi = bThi + (size_t)2 * 1536 * 512;
    unsigned short* wpTlo = wpThi + (size_t)512 * 512;

    const size_t plane_us = 6 * HSZ + (size_t)2 * 1536 * 512 + (size_t)2 * 512 * 512;
    const size_t base_fl  = HSZ + 4096 + plane_us / 2;
    float* s_g = ws + base_fl;

    const size_t avail_fl = (ws_size / 4 > base_fl) ? (ws_size / 4 - base_fl) : 0;
    // G capped at 32: 134 MB score working set fits L3 together with the
    // q/k/v planes, keeping the score write->read round-trip mostly in L3.
    int G = 32;
    while (G > 1 && (size_t)G * SEQ * SEQ > avail_fl) G >>= 1;

    split_x_kernel<<<dim3((MTOT * CDIM) / (256 * 4)), 256, 0, stream>>>(x, xhi_g, xlo_g);
    split_wT_kernel<<<dim3(32, 8), 256, 0, stream>>>(Wq, Wkv, Wp, bThi, bTlo, wpThi, wpTlo);
    qkv_mfma_kernel<<<dim3(MTOT / 128, 12), 256, 0, stream>>>(
        xhi_g, xlo_g, bThi, bTlo, bq, bkv, qhi_g, qlo_g, khi_g, klo_g, v_ws);
    vsum_kernel<<<BATCH * HEADS, 256, 0, stream>>>(v_ws, vs_ws);
    for (int bh0 = 0; bh0 < BATCH * HEADS; bh0 += G) {
        score_kernel<<<dim3(SEQ / 64, G), 256, 0, stream>>>(
            qhi_g, qlo_g, khi_g, klo_g, s_g, bh0);
        topk_pv_kernel<<<dim3(G * (SEQ / 16)), 256, 0, stream>>>(
            s_g, v_ws, vs_ws, xhi_g, xlo_g, bh0);
    }
    proj_mfma_kernel<<<dim3(MTOT / 128, CDIM / 128), 256, 0, stream>>>(
        xhi_g, xlo_g, wpThi, wpTlo, bp, out);
}

// Round 9
// 366.672 us; speedup vs baseline: 1.0711x; 1.0525x over previous
//
#include <hip/hip_runtime.h>
#include <float.h>

#define BATCH 8
#define SEQ   1024
#define CDIM  512
#define HEADS 8
#define HD    64
#define TOPK  16
#define MTOT  (BATCH*SEQ)   // 8192

typedef short bf16x8 __attribute__((ext_vector_type(8)));
typedef float f32x4v __attribute__((ext_vector_type(4)));
typedef unsigned int __attribute__((address_space(1))) guint;
typedef unsigned int __attribute__((address_space(3))) luint;

// round-to-nearest bf16 split: f = hi + lo, each bf16; |err| ~ 2^-17 |f|
__device__ inline void bf16split(float f, unsigned short& h, unsigned short& l) {
    unsigned u = __float_as_uint(f);
    unsigned hr = (u + 0x7fffu + ((u >> 16) & 1u)) >> 16;
    h = (unsigned short)hr;
    float rest = f - __uint_as_float(hr << 16);
    unsigned v = __float_as_uint(rest);
    l = (unsigned short)((v + 0x7fffu + ((v >> 16) & 1u)) >> 16);
}

// ============================================================
// Prep 1: split x into bf16 hi/lo planes (row-major [8192][512])
// ============================================================
__global__ __launch_bounds__(256) void split_x_kernel(
    const float* __restrict__ x,
    unsigned short* __restrict__ xhi, unsigned short* __restrict__ xlo)
{
    size_t i = ((size_t)blockIdx.x * 256 + threadIdx.x) * 4;
    float4 v = *(const float4*)(x + i);
    ushort4 h, l;
    bf16split(v.x, h.x, l.x); bf16split(v.y, h.y, l.y);
    bf16split(v.z, h.z, l.z); bf16split(v.w, h.w, l.w);
    *(ushort4*)(xhi + i) = h;
    *(ushort4*)(xlo + i) = l;
}

// ============================================================
// Prep 2: transpose + split weights.
//   BT  [1536][512] = concat(Wq, Wkv) columns as rows (bf16 hi/lo)
//   WpT [512][512]  = Wp columns as rows (bf16 hi/lo)
// ============================================================
__global__ __launch_bounds__(256) void split_wT_kernel(
    const float* __restrict__ Wq, const float* __restrict__ Wkv,
    const float* __restrict__ Wp,
    unsigned short* __restrict__ bThi, unsigned short* __restrict__ bTlo,
    unsigned short* __restrict__ wpThi, unsigned short* __restrict__ wpTlo)
{
    __shared__ float tile[64][65];
    const int ct = blockIdx.x, k0 = blockIdx.y * 64, t = threadIdx.x;
    const float* src; int ld, sc0, dr0;
    unsigned short *dhi, *dlo;
    if (ct < 8)       { src = Wq;  ld = CDIM;     sc0 = ct * 64;        dr0 = ct * 64;              dhi = bThi;  dlo = bTlo;  }
    else if (ct < 24) { src = Wkv; ld = 2 * CDIM; sc0 = (ct - 8) * 64;  dr0 = CDIM + (ct - 8) * 64; dhi = bThi;  dlo = bTlo;  }
    else              { src = Wp;  ld = CDIM;     sc0 = (ct - 24) * 64; dr0 = (ct - 24) * 64;       dhi = wpThi; dlo = wpTlo; }

    #pragma unroll
    for (int i = 0; i < 4; i++) {
        int f = t + i * 256;          // 0..1023
        int r = f >> 4, c4 = f & 15;  // k-row, col-segment
        float4 v = *(const float4*)(src + (size_t)(k0 + r) * ld + sc0 + c4 * 4);
        tile[c4*4+0][r] = v.x; tile[c4*4+1][r] = v.y;
        tile[c4*4+2][r] = v.z; tile[c4*4+3][r] = v.w;
    }
    __syncthreads();
    #pragma unroll
    for (int i = 0; i < 2; i++) {
        int f = t + i * 256;          // 0..511
        int c = f >> 3, ko = f & 7;
        const float* tp = &tile[c][ko * 8];
        ushort4 h0, l0, h1, l1;
        bf16split(tp[0], h0.x, l0.x); bf16split(tp[1], h0.y, l0.y);
        bf16split(tp[2], h0.z, l0.z); bf16split(tp[3], h0.w, l0.w);
        bf16split(tp[4], h1.x, l1.x); bf16split(tp[5], h1.y, l1.y);
        bf16split(tp[6], h1.z, l1.z); bf16split(tp[7], h1.w, l1.w);
        size_t o = (size_t)(dr0 + c) * CDIM + k0 + ko * 8;
        *(ushort4*)(dhi + o)     = h0; *(ushort4*)(dhi + o + 4) = h1;
        *(ushort4*)(dlo + o)     = l0; *(ushort4*)(dlo + o + 4) = l1;
    }
}

// ============================================================
// Shared MFMA GEMM core: C[128x128] = A[128xK] * B^T[128xK]^T, K=512,
// split-bf16 3-product (hi*hi + hi*lo + lo*hi), fp32 accumulate.
// Round-6 2-phase double-buffered LDS pipeline (67.6 us measured).
// ============================================================
__device__ __forceinline__ void mfma_gemm_core(
    const unsigned short* __restrict__ ahi, const unsigned short* __restrict__ alo,
    const unsigned short* __restrict__ bhi, const unsigned short* __restrict__ blo,
    int row0, int col0, int lane, int w, f32x4v acc[4][4])
{
    __shared__ __align__(16) unsigned short ah_s[2][4096], al_s[2][4096];
    __shared__ __align__(16) unsigned short bh_s[2][4096], bl_s[2][4096];

    const unsigned short* gsrc;
    unsigned short* lb[2];
    if (w == 0)      { gsrc = ahi; lb[0] = ah_s[0]; lb[1] = ah_s[1]; }
    else if (w == 1) { gsrc = alo; lb[0] = al_s[0]; lb[1] = al_s[1]; }
    else if (w == 2) { gsrc = bhi; lb[0] = bh_s[0]; lb[1] = bh_s[1]; }
    else             { gsrc = blo; lb[0] = bl_s[0]; lb[1] = bl_s[1]; }
    const int tile0 = (w < 2) ? row0 : col0;
    // per-lane source: row tile0 + c*16 + (lane&15), k-octet (lane>>4)
    const size_t goff = (size_t)(tile0 + (lane & 15)) * CDIM + (lane >> 4) * 8;
    const int wr = w >> 1, wc = w & 1;

    #pragma unroll
    for (int i = 0; i < 4; i++)
        #pragma unroll
        for (int j = 0; j < 4; j++)
            acc[i][j] = (f32x4v){0.f, 0.f, 0.f, 0.f};

    // prologue: stage K-tile 0 into buffer 0, drain, barrier
    #pragma unroll
    for (int c = 0; c < 8; c++)
        __builtin_amdgcn_global_load_lds(
            (const guint*)(gsrc + goff + (size_t)c * 16 * CDIM),
            (luint*)(lb[0] + c * 512), 16, 0, 0);
    asm volatile("s_waitcnt vmcnt(0)" ::: "memory");
    __builtin_amdgcn_s_barrier();

    int cur = 0;
    for (int kt = 0; kt < CDIM; kt += 32) {
        // issue next tile's stage into the other buffer (overlaps compute)
        if (kt + 32 < CDIM) {
            unsigned short* ln = lb[cur ^ 1];
            #pragma unroll
            for (int c = 0; c < 8; c++)
                __builtin_amdgcn_global_load_lds(
                    (const guint*)(gsrc + goff + kt + 32 + (size_t)c * 16 * CDIM),
                    (luint*)(ln + c * 512), 16, 0, 0);
        }

        // compute current buffer
        const unsigned short* ah = ah_s[cur];
        const unsigned short* al = al_s[cur];
        const unsigned short* bh = bh_s[cur];
        const unsigned short* bl = bl_s[cur];
        bf16x8 afh[4], afl[4], bfh[4], bfl[4];
        #pragma unroll
        for (int i = 0; i < 4; i++) {
            afh[i] = *(const bf16x8*)&ah[(((wr*4 + i) * 64) + lane) * 8];
            afl[i] = *(const bf16x8*)&al[(((wr*4 + i) * 64) + lane) * 8];
            bfh[i] = *(const bf16x8*)&bh[(((wc*4 + i) * 64) + lane) * 8];
            bfl[i] = *(const bf16x8*)&bl[(((wc*4 + i) * 64) + lane) * 8];
        }
        #pragma unroll
        for (int i = 0; i < 4; i++)
            #pragma unroll
            for (int j = 0; j < 4; j++) {
                acc[i][j] = __builtin_amdgcn_mfma_f32_16x16x32_bf16(bfh[j], afh[i], acc[i][j], 0, 0, 0);
                acc[i][j] = __builtin_amdgcn_mfma_f32_16x16x32_bf16(bfh[j], afl[i], acc[i][j], 0, 0, 0);
                acc[i][j] = __builtin_amdgcn_mfma_f32_16x16x32_bf16(bfl[j], afh[i], acc[i][j], 0, 0, 0);
            }

        // pin order, wait prefetch completion, barrier; swap buffers
        __builtin_amdgcn_sched_barrier(0);
        asm volatile("s_waitcnt vmcnt(0)" ::: "memory");
        __builtin_amdgcn_s_barrier();
        cur ^= 1;
    }
}

// ============================================================
// Kernel 1: QKV projection via MFMA.
// ============================================================
__global__ __launch_bounds__(256) void qkv_mfma_kernel(
    const unsigned short* __restrict__ xhi, const unsigned short* __restrict__ xlo,
    const unsigned short* __restrict__ bThi, const unsigned short* __restrict__ bTlo,
    const float* __restrict__ bq, const float* __restrict__ bkv,
    unsigned short* __restrict__ qhi_g, unsigned short* __restrict__ qlo_g,
    unsigned short* __restrict__ khi_g, unsigned short* __restrict__ klo_g,
    float* __restrict__ v_ws)
{
    const int tid = threadIdx.x, lane = tid & 63, w = tid >> 6;
    const int row0 = blockIdx.x * 128, col0 = blockIdx.y * 128;

    f32x4v acc[4][4];
    mfma_gemm_core(xhi, xlo, bThi, bTlo, row0, col0, lane, w, acc);

    const int wr = w >> 1, wc = w & 1;
    const bool isq = (col0 < CDIM);
    #pragma unroll
    for (int i = 0; i < 4; i++) {
        int rG = row0 + (wr*4 + i) * 16 + (lane & 15);
        int bb = rG >> 10, nn = rG & (SEQ - 1);
        #pragma unroll
        for (int j = 0; j < 4; j++) {
            int cG = col0 + (wc*4 + j) * 16 + (lane >> 4) * 4;
            float4 bias4 = isq ? *(const float4*)(bq + cG)
                               : *(const float4*)(bkv + cG - CDIM);
            float4 val;
            val.x = acc[i][j][0] + bias4.x;
            val.y = acc[i][j][1] + bias4.y;
            val.z = acc[i][j][2] + bias4.z;
            val.w = acc[i][j][3] + bias4.w;
            if (isq) {
                val.x = fmaxf(val.x, 0.f); val.y = fmaxf(val.y, 0.f);
                val.z = fmaxf(val.z, 0.f); val.w = fmaxf(val.w, 0.f);
                int hq = cG >> 6, d = cG & 63;
                size_t base = (((size_t)bb * HEADS + hq) * SEQ + nn) * HD + d;
                ushort4 hv, lv;
                bf16split(val.x, hv.x, lv.x); bf16split(val.y, hv.y, lv.y);
                bf16split(val.z, hv.z, lv.z); bf16split(val.w, hv.w, lv.w);
                *(ushort4*)(qhi_g + base) = hv;
                *(ushort4*)(qlo_g + base) = lv;
            } else {
                int c2 = cG - CDIM;
                int t = c2 >> 9, hq = (c2 >> 6) & 7, d = c2 & 63;
                size_t base = (((size_t)bb * HEADS + hq) * SEQ + nn) * HD + d;
                if (t == 0) {
                    ushort4 hv, lv;
                    bf16split(val.x, hv.x, lv.x); bf16split(val.y, hv.y, lv.y);
                    bf16split(val.z, hv.z, lv.z); bf16split(val.w, hv.w, lv.w);
                    *(ushort4*)(khi_g + base) = hv;
                    *(ushort4*)(klo_g + base) = lv;
                } else {
                    *(float4*)(v_ws + base) = val;
                }
            }
        }
    }
}

// ============================================================
// Kernel 2: per-(b,h) column sum of V  -> vsum[bh][64]
// ============================================================
__global__ __launch_bounds__(256) void vsum_kernel(
    const float* __restrict__ v_ws, float* __restrict__ vsum_ws)
{
    __shared__ float red[4][HD];
    const int bh = blockIdx.x;
    const int d  = threadIdx.x & 63;
    const int sl = threadIdx.x >> 6;
    const float* vh = v_ws + (size_t)bh * SEQ * HD;
    float s = 0.f;
    for (int m = sl * 256; m < (sl + 1) * 256; m++) s += vh[(size_t)m * HD + d];
    red[sl][d] = s;
    __syncthreads();
    if (threadIdx.x < HD)
        vsum_ws[(size_t)bh * HD + d] = red[0][d] + red[1][d] + red[2][d] + red[3][d];
}

// ============================================================
// Kernel A: MFMA split-bf16 scores -> global fp32 [bhl][1024][1024]
// (scaled by D^-0.5). Double-buffered K tiles.
// NEW (round 9): K-split via blockIdx.z (each block does 64 Q-rows x
// 512 K-cols) so the grid stays at 512 blocks/dispatch when G=16 —
// G was halved to make the 67 MB score buffer L3-resident (round-8
// profile: topk FETCH = 81 MB proved the G=32 round-trip hit HBM).
// ============================================================
__global__ __launch_bounds__(256) void score_kernel(
    const unsigned short* __restrict__ qhi_g, const unsigned short* __restrict__ qlo_g,
    const unsigned short* __restrict__ khi_g, const unsigned short* __restrict__ klo_g,
    float* __restrict__ s_g, int bh0)
{
    __shared__ __align__(16) short qhi_s[4096], qlo_s[4096];
    __shared__ __align__(16) short khi_s[2][4096], klo_s[2][4096];

    const int bhl = blockIdx.y;
    const int bh  = bh0 + bhl;
    const int n0  = blockIdx.x * 64;
    const int mt0 = blockIdx.z * 8;          // K-half: tiles mt0..mt0+8
    const int tid = threadIdx.x;
    const int lane = tid & 63, w = tid >> 6;
    const int r_st = tid >> 2, c4 = tid & 3;
    const size_t hb = (size_t)bh * SEQ * HD;

    const int s0 = c4 * 2, s1 = s0 + 1;
    const int cx0 = ((r_st >> 4)*2 + (s0 >> 2))*64 + (s0 & 3)*16 + (r_st & 15);
    const int cx1 = ((r_st >> 4)*2 + (s1 >> 2))*64 + (s1 & 3)*16 + (r_st & 15);

    {
        const unsigned short* qp  = qhi_g + hb + (size_t)(n0 + r_st)*HD + c4*16;
        const unsigned short* qp2 = qlo_g + hb + (size_t)(n0 + r_st)*HD + c4*16;
        uint4 h0 = *(const uint4*)qp,  h1 = *(const uint4*)(qp + 8);
        uint4 l0 = *(const uint4*)qp2, l1 = *(const uint4*)(qp2 + 8);
        *(uint4*)&qhi_s[cx0*8] = h0; *(uint4*)&qhi_s[cx1*8] = h1;
        *(uint4*)&qlo_s[cx0*8] = l0; *(uint4*)&qlo_s[cx1*8] = l1;
    }
    __syncthreads();
    bf16x8 qh[2], ql[2];
    #pragma unroll
    for (int h = 0; h < 2; h++) {
        qh[h] = *(bf16x8*)&qhi_s[((w*2 + h)*64 + lane)*8];
        ql[h] = *(bf16x8*)&qlo_s[((w*2 + h)*64 + lane)*8];
    }

    {
        const unsigned short* kp  = khi_g + hb + (size_t)(mt0*64 + r_st)*HD + c4*16;
        const unsigned short* kp2 = klo_g + hb + (size_t)(mt0*64 + r_st)*HD + c4*16;
        uint4 kh0 = *(const uint4*)kp,  kh1 = *(const uint4*)(kp + 8);
        uint4 kl0 = *(const uint4*)kp2, kl1 = *(const uint4*)(kp2 + 8);
        *(uint4*)&khi_s[0][cx0*8] = kh0; *(uint4*)&khi_s[0][cx1*8] = kh1;
        *(uint4*)&klo_s[0][cx0*8] = kl0; *(uint4*)&klo_s[0][cx1*8] = kl1;
    }
    __syncthreads();

    float* srow_base = s_g + ((size_t)bhl << 20);

    for (int mt = mt0; mt < mt0 + 8; mt++) {
        const int cur = mt & 1, nxt = cur ^ 1;
        uint4 kh0, kh1, kl0, kl1;
        if (mt + 1 < mt0 + 8) {
            const unsigned short* kp  = khi_g + hb + (size_t)((mt+1)*64 + r_st)*HD + c4*16;
            const unsigned short* kp2 = klo_g + hb + (size_t)((mt+1)*64 + r_st)*HD + c4*16;
            kh0 = *(const uint4*)kp;  kh1 = *(const uint4*)(kp + 8);
            kl0 = *(const uint4*)kp2; kl1 = *(const uint4*)(kp2 + 8);
        }

        #pragma unroll
        for (int ct = 0; ct < 4; ct++) {
            f32x4v acc = {0.f, 0.f, 0.f, 0.f};
            #pragma unroll
            for (int h = 0; h < 2; h++) {
                bf16x8 kfh = *(bf16x8*)&khi_s[cur][((ct*2 + h)*64 + lane)*8];
                bf16x8 kfl = *(bf16x8*)&klo_s[cur][((ct*2 + h)*64 + lane)*8];
                acc = __builtin_amdgcn_mfma_f32_16x16x32_bf16(qh[h], kfh, acc, 0, 0, 0);
                acc = __builtin_amdgcn_mfma_f32_16x16x32_bf16(qh[h], kfl, acc, 0, 0, 0);
                acc = __builtin_amdgcn_mfma_f32_16x16x32_bf16(ql[h], kfh, acc, 0, 0, 0);
            }
            const int col  = mt*64 + ct*16 + (lane & 15);
            const int rowb = n0 + w*16 + (lane >> 4)*4;
            float* sp = srow_base + ((size_t)rowb << 10) + col;
            #pragma unroll
            for (int rg = 0; rg < 4; rg++)
                sp[(size_t)rg << 10] = acc[rg] * 0.125f;
        }

        if (mt + 1 < mt0 + 8) {
            *(uint4*)&khi_s[nxt][cx0*8] = kh0; *(uint4*)&khi_s[nxt][cx1*8] = kh1;
            *(uint4*)&klo_s[nxt][cx0*8] = kl0; *(uint4*)&klo_s[nxt][cx1*8] = kl1;
        }
        __syncthreads();
    }
}

// ============================================================
// Kernel B: per-row top-16 + sparse softmax + PV, 2 rows/wave.
// (Round-5 version — measured best. Round-8's 4-row variant regressed:
// VGPR 72->104 cut occupancy 30->19%, dur 80.6 vs <67.6.)
// DS ops/round = 4 (ord-only reduce + ballot tie-break);
// xor1/xor2 via DPP (VALU), xor4/8/16 via ds_swizzle, xor32 via shfl.
// Packed u64 keys keep exact jax order; per-lane sorted top-4 cache
// + rare exact refill; streaming softmax/PV fused.
// ============================================================
__device__ __forceinline__ unsigned long long packkey(float f, int gidx) {
    unsigned u = __float_as_uint(f);
    unsigned o = u ^ ((unsigned)((int)u >> 31) | 0x80000000u);
    return ((unsigned long long)o << 32) | (unsigned)(~gidx);
}

struct TopCache { unsigned long long t0, t1, t2, t3; int cnt; };

__device__ __forceinline__ void cache_insert(TopCache& c, unsigned long long k) {
    bool b0 = k > c.t0, b1 = k > c.t1, b2 = k > c.t2, b3 = k > c.t3;
    c.t3 = b3 ? (b2 ? c.t2 : k) : c.t3;
    c.t2 = b2 ? (b1 ? c.t1 : k) : c.t2;
    c.t1 = b1 ? (b0 ? c.t0 : k) : c.t1;
    c.t0 = b0 ? k : c.t0;
}

__device__ __forceinline__ void cache_build(TopCache& c, const float* v, int gbase) {
    c.t0 = c.t1 = c.t2 = c.t3 = 0ull;
    #pragma unroll
    for (int j = 0; j < 16; j++) cache_insert(c, packkey(v[j], gbase + j));
    c.cnt = 4;
}

__device__ __forceinline__ void cache_pop_own(TopCache& c, bool own) {
    c.t0 = own ? c.t1 : c.t0;
    c.t1 = own ? c.t2 : c.t1;
    c.t2 = own ? c.t3 : c.t2;
    c.t3 = own ? 0ull : c.t3;
    c.cnt -= own;
}

// rebuild cache from retained values strictly below kw (extraction order
// is strictly decreasing, so remaining keys are exactly those < kw)
__device__ __forceinline__ void cache_refill(TopCache& c, const float* v,
                                             int gbase, unsigned long long kw) {
    c.t0 = c.t1 = c.t2 = c.t3 = 0ull;
    int cc = 0;
    #pragma unroll
    for (int j = 0; j < 16; j++) {
        unsigned long long k = packkey(v[j], gbase + j);
        if (k < kw) { cc++; cache_insert(c, k); }
    }
    c.cnt = cc > 4 ? 4 : cc;
}

__device__ __forceinline__ unsigned umax2(unsigned a, unsigned b) { return a > b ? a : b; }

// wave-wide max of 32-bit ord: 2 DPP (VALU) + 3 ds_swizzle + 1 shfl (DS)
__device__ __forceinline__ unsigned wave_max_ord(unsigned o) {
    unsigned p;
    p = (unsigned)__builtin_amdgcn_update_dpp(0, (int)o, 0xB1, 0xF, 0xF, true); o = umax2(o, p); // xor1 quad_perm[1,0,3,2]
    p = (unsigned)__builtin_amdgcn_update_dpp(0, (int)o, 0x4E, 0xF, 0xF, true); o = umax2(o, p); // xor2 quad_perm[2,3,0,1]
    p = (unsigned)__builtin_amdgcn_ds_swizzle((int)o, 0x101F); o = umax2(o, p);                  // xor4
    p = (unsigned)__builtin_amdgcn_ds_swizzle((int)o, 0x201F); o = umax2(o, p);                  // xor8
    p = (unsigned)__builtin_amdgcn_ds_swizzle((int)o, 0x401F); o = umax2(o, p);                  // xor16
    p = (unsigned)__shfl_xor((int)o, 32);                      o = umax2(o, p);                  // xor32
    return o;
}

__device__ __forceinline__ float ord_to_float(unsigned o) {
    return __uint_as_float(o ^ ((unsigned)((int)(~o) >> 31) | 0x80000000u));
}

__global__ __launch_bounds__(256) void topk_pv_kernel(
    const float* __restrict__ s_g, const float* __restrict__ v_ws,
    const float* __restrict__ vsum_ws,
    unsigned short* __restrict__ aohi, unsigned short* __restrict__ aolo, int bh0)
{
    const int lane = threadIdx.x & 63;
    const int wid  = (blockIdx.x * 256 + threadIdx.x) >> 6;   // 0..G*512-1
    const int bhl  = wid >> 9;
    const int pr   = wid & 511;
    const int nA   = pr * 2;
    const int bh   = bh0 + bhl;
    const int gbase = lane * 16;

    const float* srowA = s_g + ((size_t)bhl << 20) + ((size_t)nA << 10) + gbase;
    const float* srowB = srowA + SEQ;
    float vA[16], vB[16];
    #pragma unroll
    for (int i = 0; i < 4; i++) {
        float4 ta = *(const float4*)(srowA + i * 4);
        vA[i*4+0] = ta.x; vA[i*4+1] = ta.y; vA[i*4+2] = ta.z; vA[i*4+3] = ta.w;
        float4 tb = *(const float4*)(srowB + i * 4);
        vB[i*4+0] = tb.x; vB[i*4+1] = tb.y; vB[i*4+2] = tb.z; vB[i*4+3] = tb.w;
    }

    TopCache cA, cB;
    cache_build(cA, vA, gbase);
    cache_build(cB, vB, gbase);

    const float* vh = v_ws + ((size_t)bh << 16);
    const float vs = vsum_ws[(bh << 6) + lane];

    float mxA, eA, ZA, SA, mxB, eB, ZB, SB;

    // ---- round 0: establish row max -> streaming softmax state ----
    {
        unsigned oA = (unsigned)(cA.t0 >> 32);
        unsigned oB = (unsigned)(cB.t0 >> 32);
        unsigned mA = wave_max_ord(oA);
        unsigned mB = wave_max_ord(oB);
        unsigned long long blA = __ballot(oA == mA);
        unsigned long long blB = __ballot(oB == mB);
        int sA = __ffsll(blA) - 1;
        int sB = __ffsll(blB) - 1;
        unsigned loA = (unsigned)__builtin_amdgcn_readlane((int)(unsigned)cA.t0, sA);
        unsigned loB = (unsigned)__builtin_amdgcn_readlane((int)(unsigned)cB.t0, sB);
        float valA = ord_to_float(mA), valB = ord_to_float(mB);
        int idxA = (int)((~loA) & 1023u);
        int idxB = (int)((~loB) & 1023u);

        mxA = fmaxf(valA, 0.f); eA = __expf(-mxA);
        float wEA = __expf(valA - mxA);
        ZA = (float)(SEQ - TOPK) * eA + wEA;
        SA = (wEA - eA) * vh[((size_t)idxA << 6) + lane];

        mxB = fmaxf(valB, 0.f); eB = __expf(-mxB);
        float wEB = __expf(valB - mxB);
        ZB = (float)(SEQ - TOPK) * eB + wEB;
        SB = (wEB - eB) * vh[((size_t)idxB << 6) + lane];

        cache_pop_own(cA, lane == sA);    // cnt >= 3, no refill possible
        cache_pop_own(cB, lane == sB);
    }

    // ---- rounds 1..15 (two independent chains interleaved) ----
    #pragma unroll 1
    for (int t = 1; t < TOPK; t++) {
        unsigned oA = (unsigned)(cA.t0 >> 32);
        unsigned oB = (unsigned)(cB.t0 >> 32);
        unsigned mA = wave_max_ord(oA);
        unsigned mB = wave_max_ord(oB);
        unsigned long long blA = __ballot(oA == mA);
        unsigned long long blB = __ballot(oB == mB);
        int sA = __ffsll(blA) - 1;
        int sB = __ffsll(blB) - 1;
        unsigned loA = (unsigned)__builtin_amdgcn_readlane((int)(unsigned)cA.t0, sA);
        unsigned loB = (unsigned)__builtin_amdgcn_readlane((int)(unsigned)cB.t0, sB);
        float valA = ord_to_float(mA), valB = ord_to_float(mB);
        int idxA = (int)((~loA) & 1023u);
        int idxB = (int)((~loB) & 1023u);

        float wEA = __expf(valA - mxA);
        ZA += wEA;
        SA = fmaf(wEA - eA, vh[((size_t)idxA << 6) + lane], SA);

        float wEB = __expf(valB - mxB);
        ZB += wEB;
        SB = fmaf(wEB - eB, vh[((size_t)idxB << 6) + lane], SB);

        cache_pop_own(cA, lane == sA);
        cache_pop_own(cB, lane == sB);

        if (cA.cnt == 0 && t < TOPK - 1) {
            unsigned long long kwA = ((unsigned long long)mA << 32) | loA;
            cache_refill(cA, vA, gbase, kwA);
        }
        if (cB.cnt == 0 && t < TOPK - 1) {
            unsigned long long kwB = ((unsigned long long)mB << 32) | loB;
            cache_refill(cB, vB, gbase, kwB);
        }
    }

    float accA = (eA * vs + SA) / ZA;
    float accB = (eB * vs + SB) / ZB;

    const int b = bh >> 3, hh = bh & 7;
    size_t oA = (((size_t)b << 10) + nA) * CDIM + (hh << 6) + lane;
    unsigned short sh, sl;
    bf16split(accA, sh, sl);
    aohi[oA] = sh; aolo[oA] = sl;
    bf16split(accB, sh, sl);
    aohi[oA + CDIM] = sh; aolo[oA + CDIM] = sl;
}

// ============================================================
// Kernel 4: output projection via MFMA: out = ao @ Wp + bp
// ============================================================
__global__ __launch_bounds__(256) void proj_mfma_kernel(
    const unsigned short* __restrict__ aohi, const unsigned short* __restrict__ aolo,
    const unsigned short* __restrict__ wpThi, const unsigned short* __restrict__ wpTlo,
    const float* __restrict__ bp, float* __restrict__ out)
{
    const int tid = threadIdx.x, lane = tid & 63, w = tid >> 6;
    const int row0 = blockIdx.x * 128, col0 = blockIdx.y * 128;

    f32x4v acc[4][4];
    mfma_gemm_core(aohi, aolo, wpThi, wpTlo, row0, col0, lane, w, acc);

    const int wr = w >> 1, wc = w & 1;
    #pragma unroll
    for (int i = 0; i < 4; i++) {
        int rG = row0 + (wr*4 + i) * 16 + (lane & 15);
        #pragma unroll
        for (int j = 0; j < 4; j++) {
            int cG = col0 + (wc*4 + j) * 16 + (lane >> 4) * 4;
            float4 b4 = *(const float4*)(bp + cG);
            float4 val;
            val.x = acc[i][j][0] + b4.x;
            val.y = acc[i][j][1] + b4.y;
            val.z = acc[i][j][2] + b4.z;
            val.w = acc[i][j][3] + b4.w;
            *(float4*)(out + (size_t)rG * CDIM + cG) = val;
        }
    }
}

// ============================================================
extern "C" void kernel_launch(void* const* d_in, const int* in_sizes, int n_in,
                              void* d_out, int out_size, void* d_ws, size_t ws_size,
                              hipStream_t stream)
{
    const float* x   = (const float*)d_in[0];
    const float* Wq  = (const float*)d_in[1];
    const float* bq  = (const float*)d_in[2];
    const float* Wkv = (const float*)d_in[3];
    const float* bkv = (const float*)d_in[4];
    const float* Wp  = (const float*)d_in[5];
    const float* bp  = (const float*)d_in[6];
    float* out = (float*)d_out;

    const size_t HSZ = (size_t)BATCH * HEADS * SEQ * HD;   // 4,194,304
    float* ws    = (float*)d_ws;
    float* v_ws  = ws;
    float* vs_ws = ws + HSZ;
    unsigned short* qhi_g = (unsigned short*)(ws + HSZ + 4096);
    unsigned short* qlo_g = qhi_g + HSZ;
    unsigned short* khi_g = qhi_g + 2 * HSZ;
    unsigned short* klo_g = qhi_g + 3 * HSZ;
    unsigned short* xhi_g = qhi_g + 4 * HSZ;   // aliased: ao hi plane after qkv
    unsigned short* xlo_g = qhi_g + 5 * HSZ;   // aliased: ao lo plane after qkv
    unsigned short* bThi  = qhi_g + 6 * HSZ;
    unsigned short* bTlo  = bThi + (size_t)1536 * 512;
    unsigned short* wpThi = bThi + (size_t)2 * 1536 * 512;
    unsigned short* wpTlo = wpThi + (size_t)512 * 512;

    const size_t plane_us = 6 * HSZ + (size_t)2 * 1536 * 512 + (size_t)2 * 512 * 512;
    const size_t base_fl  = HSZ + 4096 + plane_us / 2;
    float* s_g = ws + base_fl;

    const size_t avail_fl = (ws_size / 4 > base_fl) ? (ws_size / 4 - base_fl) : 0;
    // G = 16: 67 MB score buffer + ~100 MB live planes < 256 MB L3, so the
    // score write->read round-trip stays L3-resident (round-8 profile showed
    // the G=32 round-trip hit HBM: topk FETCH = 81 MB ~= full score read).
    int G = 16;
    while (G > 1 && (size_t)G * SEQ * SEQ > avail_fl) G >>= 1;

    split_x_kernel<<<dim3((MTOT * CDIM) / (256 * 4)), 256, 0, stream>>>(x, xhi_g, xlo_g);
    split_wT_kernel<<<dim3(32, 8), 256, 0, stream>>>(Wq, Wkv, Wp, bThi, bTlo, wpThi, wpTlo);
    qkv_mfma_kernel<<<dim3(MTOT / 128, 12), 256, 0, stream>>>(
        xhi_g, xlo_g, bThi, bTlo, bq, bkv, qhi_g, qlo_g, khi_g, klo_g, v_ws);
    vsum_kernel<<<BATCH * HEADS, 256, 0, stream>>>(v_ws, vs_ws);
    for (int bh0 = 0; bh0 < BATCH * HEADS; bh0 += G) {
        score_kernel<<<dim3(SEQ / 64, G, 2), 256, 0, stream>>>(
            qhi_g, qlo_g, khi_g, klo_g, s_g, bh0);
        topk_pv_kernel<<<dim3(G * (SEQ / 8)), 256, 0, stream>>>(
            s_g, v_ws, vs_ws, xhi_g, xlo_g, bh0);
    }
    proj_mfma_kernel<<<dim3(MTOT / 128, CDIM / 128), 256, 0, stream>>>(
        xhi_g, xlo_g, wpThi, wpTlo, bp, out);
}

// Round 10
// 339.227 us; speedup vs baseline: 1.1577x; 1.0809x over previous
//
#include <hip/hip_runtime.h>
#include <float.h>

#define BATCH 8
#define SEQ   1024
#define CDIM  512
#define HEADS 8
#define HD    64
#define TOPK  16
#define MTOT  (BATCH*SEQ)   // 8192

typedef short bf16x8 __attribute__((ext_vector_type(8)));
typedef float f32x4v __attribute__((ext_vector_type(4)));
typedef unsigned int __attribute__((address_space(1))) guint;
typedef unsigned int __attribute__((address_space(3))) luint;

// round-to-nearest bf16 split: f = hi + lo, each bf16; |err| ~ 2^-17 |f|
__device__ inline void bf16split(float f, unsigned short& h, unsigned short& l) {
    unsigned u = __float_as_uint(f);
    unsigned hr = (u + 0x7fffu + ((u >> 16) & 1u)) >> 16;
    h = (unsigned short)hr;
    float rest = f - __uint_as_float(hr << 16);
    unsigned v = __float_as_uint(rest);
    l = (unsigned short)((v + 0x7fffu + ((v >> 16) & 1u)) >> 16);
}

// ============================================================
// Prep 1: split x into bf16 hi/lo planes (row-major [8192][512])
// ============================================================
__global__ __launch_bounds__(256) void split_x_kernel(
    const float* __restrict__ x,
    unsigned short* __restrict__ xhi, unsigned short* __restrict__ xlo)
{
    size_t i = ((size_t)blockIdx.x * 256 + threadIdx.x) * 4;
    float4 v = *(const float4*)(x + i);
    ushort4 h, l;
    bf16split(v.x, h.x, l.x); bf16split(v.y, h.y, l.y);
    bf16split(v.z, h.z, l.z); bf16split(v.w, h.w, l.w);
    *(ushort4*)(xhi + i) = h;
    *(ushort4*)(xlo + i) = l;
}

// ============================================================
// Prep 2: transpose + split weights.
//   BT  [1536][512] = concat(Wq, Wkv) columns as rows (bf16 hi/lo)
//   WpT [512][512]  = Wp columns as rows (bf16 hi/lo)
// ============================================================
__global__ __launch_bounds__(256) void split_wT_kernel(
    const float* __restrict__ Wq, const float* __restrict__ Wkv,
    const float* __restrict__ Wp,
    unsigned short* __restrict__ bThi, unsigned short* __restrict__ bTlo,
    unsigned short* __restrict__ wpThi, unsigned short* __restrict__ wpTlo)
{
    __shared__ float tile[64][65];
    const int ct = blockIdx.x, k0 = blockIdx.y * 64, t = threadIdx.x;
    const float* src; int ld, sc0, dr0;
    unsigned short *dhi, *dlo;
    if (ct < 8)       { src = Wq;  ld = CDIM;     sc0 = ct * 64;        dr0 = ct * 64;              dhi = bThi;  dlo = bTlo;  }
    else if (ct < 24) { src = Wkv; ld = 2 * CDIM; sc0 = (ct - 8) * 64;  dr0 = CDIM + (ct - 8) * 64; dhi = bThi;  dlo = bTlo;  }
    else              { src = Wp;  ld = CDIM;     sc0 = (ct - 24) * 64; dr0 = (ct - 24) * 64;       dhi = wpThi; dlo = wpTlo; }

    #pragma unroll
    for (int i = 0; i < 4; i++) {
        int f = t + i * 256;          // 0..1023
        int r = f >> 4, c4 = f & 15;  // k-row, col-segment
        float4 v = *(const float4*)(src + (size_t)(k0 + r) * ld + sc0 + c4 * 4);
        tile[c4*4+0][r] = v.x; tile[c4*4+1][r] = v.y;
        tile[c4*4+2][r] = v.z; tile[c4*4+3][r] = v.w;
    }
    __syncthreads();
    #pragma unroll
    for (int i = 0; i < 2; i++) {
        int f = t + i * 256;          // 0..511
        int c = f >> 3, ko = f & 7;
        const float* tp = &tile[c][ko * 8];
        ushort4 h0, l0, h1, l1;
        bf16split(tp[0], h0.x, l0.x); bf16split(tp[1], h0.y, l0.y);
        bf16split(tp[2], h0.z, l0.z); bf16split(tp[3], h0.w, l0.w);
        bf16split(tp[4], h1.x, l1.x); bf16split(tp[5], h1.y, l1.y);
        bf16split(tp[6], h1.z, l1.z); bf16split(tp[7], h1.w, l1.w);
        size_t o = (size_t)(dr0 + c) * CDIM + k0 + ko * 8;
        *(ushort4*)(dhi + o)     = h0; *(ushort4*)(dhi + o + 4) = h1;
        *(ushort4*)(dlo + o)     = l0; *(ushort4*)(dlo + o + 4) = l1;
    }
}

// ============================================================
// Shared MFMA GEMM core: C[128x128] = A[128xK] * B^T[128xK]^T, K=512,
// split-bf16 3-product (hi*hi + hi*lo + lo*hi), fp32 accumulate.
// Round-6 2-phase double-buffered LDS pipeline (67.6 us measured).
// ============================================================
__device__ __forceinline__ void mfma_gemm_core(
    const unsigned short* __restrict__ ahi, const unsigned short* __restrict__ alo,
    const unsigned short* __restrict__ bhi, const unsigned short* __restrict__ blo,
    int row0, int col0, int lane, int w, f32x4v acc[4][4])
{
    __shared__ __align__(16) unsigned short ah_s[2][4096], al_s[2][4096];
    __shared__ __align__(16) unsigned short bh_s[2][4096], bl_s[2][4096];

    const unsigned short* gsrc;
    unsigned short* lb[2];
    if (w == 0)      { gsrc = ahi; lb[0] = ah_s[0]; lb[1] = ah_s[1]; }
    else if (w == 1) { gsrc = alo; lb[0] = al_s[0]; lb[1] = al_s[1]; }
    else if (w == 2) { gsrc = bhi; lb[0] = bh_s[0]; lb[1] = bh_s[1]; }
    else             { gsrc = blo; lb[0] = bl_s[0]; lb[1] = bl_s[1]; }
    const int tile0 = (w < 2) ? row0 : col0;
    // per-lane source: row tile0 + c*16 + (lane&15), k-octet (lane>>4)
    const size_t goff = (size_t)(tile0 + (lane & 15)) * CDIM + (lane >> 4) * 8;
    const int wr = w >> 1, wc = w & 1;

    #pragma unroll
    for (int i = 0; i < 4; i++)
        #pragma unroll
        for (int j = 0; j < 4; j++)
            acc[i][j] = (f32x4v){0.f, 0.f, 0.f, 0.f};

    // prologue: stage K-tile 0 into buffer 0, drain, barrier
    #pragma unroll
    for (int c = 0; c < 8; c++)
        __builtin_amdgcn_global_load_lds(
            (const guint*)(gsrc + goff + (size_t)c * 16 * CDIM),
            (luint*)(lb[0] + c * 512), 16, 0, 0);
    asm volatile("s_waitcnt vmcnt(0)" ::: "memory");
    __builtin_amdgcn_s_barrier();

    int cur = 0;
    for (int kt = 0; kt < CDIM; kt += 32) {
        // issue next tile's stage into the other buffer (overlaps compute)
        if (kt + 32 < CDIM) {
            unsigned short* ln = lb[cur ^ 1];
            #pragma unroll
            for (int c = 0; c < 8; c++)
                __builtin_amdgcn_global_load_lds(
                    (const guint*)(gsrc + goff + kt + 32 + (size_t)c * 16 * CDIM),
                    (luint*)(ln + c * 512), 16, 0, 0);
        }

        // compute current buffer
        const unsigned short* ah = ah_s[cur];
        const unsigned short* al = al_s[cur];
        const unsigned short* bh = bh_s[cur];
        const unsigned short* bl = bl_s[cur];
        bf16x8 afh[4], afl[4], bfh[4], bfl[4];
        #pragma unroll
        for (int i = 0; i < 4; i++) {
            afh[i] = *(const bf16x8*)&ah[(((wr*4 + i) * 64) + lane) * 8];
            afl[i] = *(const bf16x8*)&al[(((wr*4 + i) * 64) + lane) * 8];
            bfh[i] = *(const bf16x8*)&bh[(((wc*4 + i) * 64) + lane) * 8];
            bfl[i] = *(const bf16x8*)&bl[(((wc*4 + i) * 64) + lane) * 8];
        }
        #pragma unroll
        for (int i = 0; i < 4; i++)
            #pragma unroll
            for (int j = 0; j < 4; j++) {
                acc[i][j] = __builtin_amdgcn_mfma_f32_16x16x32_bf16(bfh[j], afh[i], acc[i][j], 0, 0, 0);
                acc[i][j] = __builtin_amdgcn_mfma_f32_16x16x32_bf16(bfh[j], afl[i], acc[i][j], 0, 0, 0);
                acc[i][j] = __builtin_amdgcn_mfma_f32_16x16x32_bf16(bfl[j], afh[i], acc[i][j], 0, 0, 0);
            }

        // pin order, wait prefetch completion, barrier; swap buffers
        __builtin_amdgcn_sched_barrier(0);
        asm volatile("s_waitcnt vmcnt(0)" ::: "memory");
        __builtin_amdgcn_s_barrier();
        cur ^= 1;
    }
}

// ============================================================
// Kernel 1: QKV projection via MFMA.
// ============================================================
__global__ __launch_bounds__(256) void qkv_mfma_kernel(
    const unsigned short* __restrict__ xhi, const unsigned short* __restrict__ xlo,
    const unsigned short* __restrict__ bThi, const unsigned short* __restrict__ bTlo,
    const float* __restrict__ bq, const float* __restrict__ bkv,
    unsigned short* __restrict__ qhi_g, unsigned short* __restrict__ qlo_g,
    unsigned short* __restrict__ khi_g, unsigned short* __restrict__ klo_g,
    float* __restrict__ v_ws)
{
    const int tid = threadIdx.x, lane = tid & 63, w = tid >> 6;
    const int row0 = blockIdx.x * 128, col0 = blockIdx.y * 128;

    f32x4v acc[4][4];
    mfma_gemm_core(xhi, xlo, bThi, bTlo, row0, col0, lane, w, acc);

    const int wr = w >> 1, wc = w & 1;
    const bool isq = (col0 < CDIM);
    #pragma unroll
    for (int i = 0; i < 4; i++) {
        int rG = row0 + (wr*4 + i) * 16 + (lane & 15);
        int bb = rG >> 10, nn = rG & (SEQ - 1);
        #pragma unroll
        for (int j = 0; j < 4; j++) {
            int cG = col0 + (wc*4 + j) * 16 + (lane >> 4) * 4;
            float4 bias4 = isq ? *(const float4*)(bq + cG)
                               : *(const float4*)(bkv + cG - CDIM);
            float4 val;
            val.x = acc[i][j][0] + bias4.x;
            val.y = acc[i][j][1] + bias4.y;
            val.z = acc[i][j][2] + bias4.z;
            val.w = acc[i][j][3] + bias4.w;
            if (isq) {
                val.x = fmaxf(val.x, 0.f); val.y = fmaxf(val.y, 0.f);
                val.z = fmaxf(val.z, 0.f); val.w = fmaxf(val.w, 0.f);
                int hq = cG >> 6, d = cG & 63;
                size_t base = (((size_t)bb * HEADS + hq) * SEQ + nn) * HD + d;
                ushort4 hv, lv;
                bf16split(val.x, hv.x, lv.x); bf16split(val.y, hv.y, lv.y);
                bf16split(val.z, hv.z, lv.z); bf16split(val.w, hv.w, lv.w);
                *(ushort4*)(qhi_g + base) = hv;
                *(ushort4*)(qlo_g + base) = lv;
            } else {
                int c2 = cG - CDIM;
                int t = c2 >> 9, hq = (c2 >> 6) & 7, d = c2 & 63;
                size_t base = (((size_t)bb * HEADS + hq) * SEQ + nn) * HD + d;
                if (t == 0) {
                    ushort4 hv, lv;
                    bf16split(val.x, hv.x, lv.x); bf16split(val.y, hv.y, lv.y);
                    bf16split(val.z, hv.z, lv.z); bf16split(val.w, hv.w, lv.w);
                    *(ushort4*)(khi_g + base) = hv;
                    *(ushort4*)(klo_g + base) = lv;
                } else {
                    *(float4*)(v_ws + base) = val;
                }
            }
        }
    }
}

// ============================================================
// Kernel 2: per-(b,h) column sum of V  -> vsum[bh][64]
// ============================================================
__global__ __launch_bounds__(256) void vsum_kernel(
    const float* __restrict__ v_ws, float* __restrict__ vsum_ws)
{
    __shared__ float red[4][HD];
    const int bh = blockIdx.x;
    const int d  = threadIdx.x & 63;
    const int sl = threadIdx.x >> 6;
    const float* vh = v_ws + (size_t)bh * SEQ * HD;
    float s = 0.f;
    for (int m = sl * 256; m < (sl + 1) * 256; m++) s += vh[(size_t)m * HD + d];
    red[sl][d] = s;
    __syncthreads();
    if (threadIdx.x < HD)
        vsum_ws[(size_t)bh * HD + d] = red[0][d] + red[1][d] + red[2][d] + red[3][d];
}

// ============================================================
// Kernel A: MFMA split-bf16 scores -> global fp32 [bhl][1024][1024]
// (scaled by D^-0.5). Double-buffered K tiles. (Round-6 form: no
// K-split — round-9's G=16 + z-split added ~20 us of kernel-boundary
// overhead for no L3 benefit. G=32, 2 loop iterations, is best.)
// ============================================================
__global__ __launch_bounds__(256) void score_kernel(
    const unsigned short* __restrict__ qhi_g, const unsigned short* __restrict__ qlo_g,
    const unsigned short* __restrict__ khi_g, const unsigned short* __restrict__ klo_g,
    float* __restrict__ s_g, int bh0)
{
    __shared__ __align__(16) short qhi_s[4096], qlo_s[4096];
    __shared__ __align__(16) short khi_s[2][4096], klo_s[2][4096];

    const int bhl = blockIdx.y;
    const int bh  = bh0 + bhl;
    const int n0  = blockIdx.x * 64;
    const int tid = threadIdx.x;
    const int lane = tid & 63, w = tid >> 6;
    const int r_st = tid >> 2, c4 = tid & 3;
    const size_t hb = (size_t)bh * SEQ * HD;

    const int s0 = c4 * 2, s1 = s0 + 1;
    const int cx0 = ((r_st >> 4)*2 + (s0 >> 2))*64 + (s0 & 3)*16 + (r_st & 15);
    const int cx1 = ((r_st >> 4)*2 + (s1 >> 2))*64 + (s1 & 3)*16 + (r_st & 15);

    {
        const unsigned short* qp  = qhi_g + hb + (size_t)(n0 + r_st)*HD + c4*16;
        const unsigned short* qp2 = qlo_g + hb + (size_t)(n0 + r_st)*HD + c4*16;
        uint4 h0 = *(const uint4*)qp,  h1 = *(const uint4*)(qp + 8);
        uint4 l0 = *(const uint4*)qp2, l1 = *(const uint4*)(qp2 + 8);
        *(uint4*)&qhi_s[cx0*8] = h0; *(uint4*)&qhi_s[cx1*8] = h1;
        *(uint4*)&qlo_s[cx0*8] = l0; *(uint4*)&qlo_s[cx1*8] = l1;
    }
    __syncthreads();
    bf16x8 qh[2], ql[2];
    #pragma unroll
    for (int h = 0; h < 2; h++) {
        qh[h] = *(bf16x8*)&qhi_s[((w*2 + h)*64 + lane)*8];
        ql[h] = *(bf16x8*)&qlo_s[((w*2 + h)*64 + lane)*8];
    }

    {
        const unsigned short* kp  = khi_g + hb + (size_t)r_st*HD + c4*16;
        const unsigned short* kp2 = klo_g + hb + (size_t)r_st*HD + c4*16;
        uint4 kh0 = *(const uint4*)kp,  kh1 = *(const uint4*)(kp + 8);
        uint4 kl0 = *(const uint4*)kp2, kl1 = *(const uint4*)(kp2 + 8);
        *(uint4*)&khi_s[0][cx0*8] = kh0; *(uint4*)&khi_s[0][cx1*8] = kh1;
        *(uint4*)&klo_s[0][cx0*8] = kl0; *(uint4*)&klo_s[0][cx1*8] = kl1;
    }
    __syncthreads();

    float* srow_base = s_g + ((size_t)bhl << 20);

    for (int mt = 0; mt < SEQ / 64; mt++) {
        const int cur = mt & 1, nxt = cur ^ 1;
        uint4 kh0, kh1, kl0, kl1;
        if (mt + 1 < SEQ / 64) {
            const unsigned short* kp  = khi_g + hb + (size_t)((mt+1)*64 + r_st)*HD + c4*16;
            const unsigned short* kp2 = klo_g + hb + (size_t)((mt+1)*64 + r_st)*HD + c4*16;
            kh0 = *(const uint4*)kp;  kh1 = *(const uint4*)(kp + 8);
            kl0 = *(const uint4*)kp2; kl1 = *(const uint4*)(kp2 + 8);
        }

        #pragma unroll
        for (int ct = 0; ct < 4; ct++) {
            f32x4v acc = {0.f, 0.f, 0.f, 0.f};
            #pragma unroll
            for (int h = 0; h < 2; h++) {
                bf16x8 kfh = *(bf16x8*)&khi_s[cur][((ct*2 + h)*64 + lane)*8];
                bf16x8 kfl = *(bf16x8*)&klo_s[cur][((ct*2 + h)*64 + lane)*8];
                acc = __builtin_amdgcn_mfma_f32_16x16x32_bf16(qh[h], kfh, acc, 0, 0, 0);
                acc = __builtin_amdgcn_mfma_f32_16x16x32_bf16(qh[h], kfl, acc, 0, 0, 0);
                acc = __builtin_amdgcn_mfma_f32_16x16x32_bf16(ql[h], kfh, acc, 0, 0, 0);
            }
            const int col  = mt*64 + ct*16 + (lane & 15);
            const int rowb = n0 + w*16 + (lane >> 4)*4;
            float* sp = srow_base + ((size_t)rowb << 10) + col;
            #pragma unroll
            for (int rg = 0; rg < 4; rg++)
                sp[(size_t)rg << 10] = acc[rg] * 0.125f;
        }

        if (mt + 1 < SEQ / 64) {
            *(uint4*)&khi_s[nxt][cx0*8] = kh0; *(uint4*)&khi_s[nxt][cx1*8] = kh1;
            *(uint4*)&klo_s[nxt][cx0*8] = kl0; *(uint4*)&klo_s[nxt][cx1*8] = kl1;
        }
        __syncthreads();
    }
}

// ============================================================
// Kernel B: per-row top-16 + sparse softmax + PV, 1 row/wave with
// DEFERRED PV (round 10). Theory: r5's streaming fusion put a
// dependent V-row gather (idx known only after the round's reduce)
// on every round's critical path — 16 x ~200-400cy of serial load
// latency per row. Now: rounds compute only (wexp, idx), parked in
// 512B of per-wave LDS (keeps the rounds loop rolled, arrays never
// spill to scratch); then 16 INDEPENDENT V gathers + FMA drain.
// 1 row/wave doubles TLP at ~same VGPR. Extraction math unchanged
// (packed u64 keys, exact jax tie order, top-4 cache + rare refill).
// ============================================================
__device__ __forceinline__ unsigned long long packkey(float f, int gidx) {
    unsigned u = __float_as_uint(f);
    unsigned o = u ^ ((unsigned)((int)u >> 31) | 0x80000000u);
    return ((unsigned long long)o << 32) | (unsigned)(~gidx);
}

struct TopCache { unsigned long long t0, t1, t2, t3; int cnt; };

__device__ __forceinline__ void cache_insert(TopCache& c, unsigned long long k) {
    bool b0 = k > c.t0, b1 = k > c.t1, b2 = k > c.t2, b3 = k > c.t3;
    c.t3 = b3 ? (b2 ? c.t2 : k) : c.t3;
    c.t2 = b2 ? (b1 ? c.t1 : k) : c.t2;
    c.t1 = b1 ? (b0 ? c.t0 : k) : c.t1;
    c.t0 = b0 ? k : c.t0;
}

__device__ __forceinline__ void cache_build(TopCache& c, const float* v, int gbase) {
    c.t0 = c.t1 = c.t2 = c.t3 = 0ull;
    #pragma unroll
    for (int j = 0; j < 16; j++) cache_insert(c, packkey(v[j], gbase + j));
    c.cnt = 4;
}

__device__ __forceinline__ void cache_pop_own(TopCache& c, bool own) {
    c.t0 = own ? c.t1 : c.t0;
    c.t1 = own ? c.t2 : c.t1;
    c.t2 = own ? c.t3 : c.t2;
    c.t3 = own ? 0ull : c.t3;
    c.cnt -= own;
}

// rebuild cache from retained values strictly below kw (extraction order
// is strictly decreasing, so remaining keys are exactly those < kw)
__device__ __forceinline__ void cache_refill(TopCache& c, const float* v,
                                             int gbase, unsigned long long kw) {
    c.t0 = c.t1 = c.t2 = c.t3 = 0ull;
    int cc = 0;
    #pragma unroll
    for (int j = 0; j < 16; j++) {
        unsigned long long k = packkey(v[j], gbase + j);
        if (k < kw) { cc++; cache_insert(c, k); }
    }
    c.cnt = cc > 4 ? 4 : cc;
}

__device__ __forceinline__ unsigned umax2(unsigned a, unsigned b) { return a > b ? a : b; }

// wave-wide max of 32-bit ord: 2 DPP (VALU) + 3 ds_swizzle + 1 shfl (DS)
__device__ __forceinline__ unsigned wave_max_ord(unsigned o) {
    unsigned p;
    p = (unsigned)__builtin_amdgcn_update_dpp(0, (int)o, 0xB1, 0xF, 0xF, true); o = umax2(o, p); // xor1 quad_perm[1,0,3,2]
    p = (unsigned)__builtin_amdgcn_update_dpp(0, (int)o, 0x4E, 0xF, 0xF, true); o = umax2(o, p); // xor2 quad_perm[2,3,0,1]
    p = (unsigned)__builtin_amdgcn_ds_swizzle((int)o, 0x101F); o = umax2(o, p);                  // xor4
    p = (unsigned)__builtin_amdgcn_ds_swizzle((int)o, 0x201F); o = umax2(o, p);                  // xor8
    p = (unsigned)__builtin_amdgcn_ds_swizzle((int)o, 0x401F); o = umax2(o, p);                  // xor16
    p = (unsigned)__shfl_xor((int)o, 32);                      o = umax2(o, p);                  // xor32
    return o;
}

__device__ __forceinline__ float ord_to_float(unsigned o) {
    return __uint_as_float(o ^ ((unsigned)((int)(~o) >> 31) | 0x80000000u));
}

__global__ __launch_bounds__(256) void topk_pv_kernel(
    const float* __restrict__ s_g, const float* __restrict__ v_ws,
    const float* __restrict__ vsum_ws,
    unsigned short* __restrict__ aohi, unsigned short* __restrict__ aolo, int bh0)
{
    __shared__ unsigned pair_s[4][TOPK][2];   // per-wave (wexp bits, idx)

    const int lane = threadIdx.x & 63;
    const int wv   = threadIdx.x >> 6;
    const int wid  = (blockIdx.x * 256 + threadIdx.x) >> 6;   // 0..G*1024-1
    const int bhl  = wid >> 10;
    const int n    = wid & (SEQ - 1);
    const int bh   = bh0 + bhl;
    const int gbase = lane * 16;

    const float* srow = s_g + ((size_t)bhl << 20) + ((size_t)n << 10) + gbase;
    float v[16];
    #pragma unroll
    for (int i = 0; i < 4; i++) {
        float4 t4 = *(const float4*)(srow + i * 4);
        v[i*4+0] = t4.x; v[i*4+1] = t4.y; v[i*4+2] = t4.z; v[i*4+3] = t4.w;
    }

    TopCache c;
    cache_build(c, v, gbase);

    float mx, e, Z;

    // ---- round 0: establish row max ----
    {
        unsigned o = (unsigned)(c.t0 >> 32);
        unsigned m = wave_max_ord(o);
        unsigned long long bl = __ballot(o == m);
        int s = __ffsll(bl) - 1;
        unsigned lo = (unsigned)__builtin_amdgcn_readlane((int)(unsigned)c.t0, s);
        float val = ord_to_float(m);

        mx = fmaxf(val, 0.f);
        e  = __expf(-mx);
        float wE = __expf(val - mx);
        Z = (float)(SEQ - TOPK) * e + wE;
        if (lane == 0) {
            pair_s[wv][0][0] = __float_as_uint(wE);
            pair_s[wv][0][1] = (~lo) & 1023u;
        }
        cache_pop_own(c, lane == s);     // cnt >= 3, no refill possible
    }

    // ---- rounds 1..15: extraction only, no global loads ----
    #pragma unroll 1
    for (int t = 1; t < TOPK; t++) {
        unsigned o = (unsigned)(c.t0 >> 32);
        unsigned m = wave_max_ord(o);
        unsigned long long bl = __ballot(o == m);
        int s = __ffsll(bl) - 1;
        unsigned lo = (unsigned)__builtin_amdgcn_readlane((int)(unsigned)c.t0, s);
        float val = ord_to_float(m);

        float wE = __expf(val - mx);
        Z += wE;
        if (lane == 0) {
            pair_s[wv][t][0] = __float_as_uint(wE);
            pair_s[wv][t][1] = (~lo) & 1023u;
        }
        cache_pop_own(c, lane == s);

        if (c.cnt == 0 && t < TOPK - 1) {
            unsigned long long kw = ((unsigned long long)m << 32) | lo;
            cache_refill(c, v, gbase, kw);
        }
    }

    // ---- deferred PV: read pairs (wave-local LDS), 16 independent gathers ----
    float wexp[TOPK]; int mi[TOPK];
    #pragma unroll
    for (int t = 0; t < TOPK; t++) {
        wexp[t] = __uint_as_float(pair_s[wv][t][0]);
        mi[t]   = (int)pair_s[wv][t][1];
    }
    const float* vhp = v_ws + ((size_t)bh << 16);
    float vr[TOPK];
    #pragma unroll
    for (int t = 0; t < TOPK; t++)
        vr[t] = vhp[((size_t)mi[t] << 6) + lane];

    float acc = e * vsum_ws[(bh << 6) + lane];
    #pragma unroll
    for (int t = 0; t < TOPK; t++)
        acc = fmaf(wexp[t] - e, vr[t], acc);
    acc /= Z;

    const int b = bh >> 3, hh = bh & 7;
    size_t oo = (((size_t)b << 10) + n) * CDIM + (hh << 6) + lane;
    unsigned short sh, sl;
    bf16split(acc, sh, sl);
    aohi[oo] = sh;
    aolo[oo] = sl;
}

// ============================================================
// Kernel 4: output projection via MFMA: out = ao @ Wp + bp
// ============================================================
__global__ __launch_bounds__(256) void proj_mfma_kernel(
    const unsigned short* __restrict__ aohi, const unsigned short* __restrict__ aolo,
    const unsigned short* __restrict__ wpThi, const unsigned short* __restrict__ wpTlo,
    const float* __restrict__ bp, float* __restrict__ out)
{
    const int tid = threadIdx.x, lane = tid & 63, w = tid >> 6;
    const int row0 = blockIdx.x * 128, col0 = blockIdx.y * 128;

    f32x4v acc[4][4];
    mfma_gemm_core(aohi, aolo, wpThi, wpTlo, row0, col0, lane, w, acc);

    const int wr = w >> 1, wc = w & 1;
    #pragma unroll
    for (int i = 0; i < 4; i++) {
        int rG = row0 + (wr*4 + i) * 16 + (lane & 15);
        #pragma unroll
        for (int j = 0; j < 4; j++) {
            int cG = col0 + (wc*4 + j) * 16 + (lane >> 4) * 4;
            float4 b4 = *(const float4*)(bp + cG);
            float4 val;
            val.x = acc[i][j][0] + b4.x;
            val.y = acc[i][j][1] + b4.y;
            val.z = acc[i][j][2] + b4.z;
            val.w = acc[i][j][3] + b4.w;
            *(float4*)(out + (size_t)rG * CDIM + cG) = val;
        }
    }
}

// ============================================================
extern "C" void kernel_launch(void* const* d_in, const int* in_sizes, int n_in,
                              void* d_out, int out_size, void* d_ws, size_t ws_size,
                              hipStream_t stream)
{
    const float* x   = (const float*)d_in[0];
    const float* Wq  = (const float*)d_in[1];
    const float* bq  = (const float*)d_in[2];
    const float* Wkv = (const float*)d_in[3];
    const float* bkv = (const float*)d_in[4];
    const float* Wp  = (const float*)d_in[5];
    const float* bp  = (const float*)d_in[6];
    float* out = (float*)d_out;

    const size_t HSZ = (size_t)BATCH * HEADS * SEQ * HD;   // 4,194,304
    float* ws    = (float*)d_ws;
    float* v_ws  = ws;
    float* vs_ws = ws + HSZ;
    unsigned short* qhi_g = (unsigned short*)(ws + HSZ + 4096);
    unsigned short* qlo_g = qhi_g + HSZ;
    unsigned short* khi_g = qhi_g + 2 * HSZ;
    unsigned short* klo_g = qhi_g + 3 * HSZ;
    unsigned short* xhi_g = qhi_g + 4 * HSZ;   // aliased: ao hi plane after qkv
    unsigned short* xlo_g = qhi_g + 5 * HSZ;   // aliased: ao lo plane after qkv
    unsigned short* bThi  = qhi_g + 6 * HSZ;
    unsigned short* bTlo  = bThi + (size_t)1536 * 512;
    unsigned short* wpThi = bThi + (size_t)2 * 1536 * 512;
    unsigned short* wpTlo = wpThi + (size_t)512 * 512;

    const size_t plane_us = 6 * HSZ + (size_t)2 * 1536 * 512 + (size_t)2 * 512 * 512;
    const size_t base_fl  = HSZ + 4096 + plane_us / 2;
    float* s_g = ws + base_fl;

    const size_t avail_fl = (ws_size / 4 > base_fl) ? (ws_size / 4 - base_fl) : 0;
    // G = 32 (round-6 best config): 2 loop iterations. r9's G=16 (4 iters)
    // added ~20 us of kernel-boundary overhead with no L3 benefit.
    int G = 32;
    while (G > 1 && (size_t)G * SEQ * SEQ > avail_fl) G >>= 1;

    split_x_kernel<<<dim3((MTOT * CDIM) / (256 * 4)), 256, 0, stream>>>(x, xhi_g, xlo_g);
    split_wT_kernel<<<dim3(32, 8), 256, 0, stream>>>(Wq, Wkv, Wp, bThi, bTlo, wpThi, wpTlo);
    qkv_mfma_kernel<<<dim3(MTOT / 128, 12), 256, 0, stream>>>(
        xhi_g, xlo_g, bThi, bTlo, bq, bkv, qhi_g, qlo_g, khi_g, klo_g, v_ws);
    vsum_kernel<<<BATCH * HEADS, 256, 0, stream>>>(v_ws, vs_ws);
    for (int bh0 = 0; bh0 < BATCH * HEADS; bh0 += G) {
        score_kernel<<<dim3(SEQ / 64, G), 256, 0, stream>>>(
            qhi_g, qlo_g, khi_g, klo_g, s_g, bh0);
        topk_pv_kernel<<<dim3(G * (SEQ / 4)), 256, 0, stream>>>(
            s_g, v_ws, vs_ws, xhi_g, xlo_g, bh0);
    }
    proj_mfma_kernel<<<dim3(MTOT / 128, CDIM / 128), 256, 0, stream>>>(
        xhi_g, xlo_g, wpThi, wpTlo, bp, out);
}